// Round 4
// baseline (322.284 us; speedup 1.0000x reference)
//
#include <hip/hip_runtime.h>
#include <hip/hip_bf16.h>
#include <hip/hip_cooperative_groups.h>

namespace cg = cooperative_groups;

#define BB 2
#define NN 20000
#define EE 200000
#define INF 256
#define OUTF 32
#define NH 4
#define HF 128          // NH*OUTF
#define NEG_SLOPE 0.2f
#define GEMM_BLOCKS 625  // 40000 rows / 64
#define EDGE_BLOCKS 782  // fallback path: ceil(200000/256)
#define CAP 48           // slots per node (deg ~ Poisson(10); overflow -> list)
#define OVF_CAP 8192

using bf16 = __hip_bfloat16;
typedef __attribute__((ext_vector_type(8))) short bf16x8;
typedef __attribute__((ext_vector_type(4))) float f32x4;
typedef unsigned long long u64;

__device__ __forceinline__ float bf2f(unsigned short s){ return __uint_as_float((unsigned)s << 16); }
__device__ __forceinline__ ushort f2bf_bits(float f){
    __hip_bfloat16 b = __float2bfloat16(f);
    return *(ushort*)&b;
}

__device__ __forceinline__ int get_src(const int* ei, int e, int f64){
    return f64 ? ei[2 * e] : ei[e];
}
__device__ __forceinline__ int get_dst(const int* ei, int e, int f64){
    return f64 ? ei[2 * EE + 2 * e] : ei[EE + e];
}

// ============================================================================
// FUSED single-launch cooperative kernel.
// phase0: per-block dtype detect + init cnt/last_e64 + wbf convert
// phase1: edge build (1 atomic/edge, packed u64 slot = ((e+1)<<16)|dst)
//         + MFMA GEMM (blocks < GEMM_BLOCKS)
// phase2: per-node softmax + atomic-free aggregate (dst directly from slot)
// phase3: overflow fix (uniformly skipped when ovf_cnt == 0)
// ============================================================================
__global__ __launch_bounds__(256, 4)
void k_fused(const void* __restrict__ xv_, const int* __restrict__ ei,
             const void* __restrict__ Wv, const void* __restrict__ av,
             ushort* __restrict__ wbf, ushort* __restrict__ h,
             float* __restrict__ alpha_s, float* __restrict__ alpha_d,
             u64* __restrict__ last_e64, int* __restrict__ cnt,
             u64* __restrict__ slots, int* __restrict__ ovf_cnt,
             int* __restrict__ ovf_list, float* __restrict__ aw,
             float* __restrict__ out_f)
{
    cg::grid_group grid = cg::this_grid();
    const int tid = threadIdx.x;
    const int nb  = gridDim.x;
    const int gt  = blockIdx.x * 256 + tid;
    const int nthreads = nb * 256;

    // ---------------- phase 0 ----------------
    __shared__ int sh_big, sh_nz;
    if (tid == 0){ sh_big = 0; sh_nz = 0; }
    __syncthreads();
    {
        const ushort* xr = (const ushort*)xv_;
        int big = 0;
        for (int k = tid; k < 2048; k += 256){
            unsigned e = ((unsigned)xr[2 * k] >> 7) & 0xff;  // bf16-exp of fp32 low half
            if (e >= 0xC0) big++;                            // impossible for N(0,1) bf16
        }
        int nz = 0;
        for (int k = tid; k < 1024; k += 256){
            if (ei[2 * k + 1] != 0) nz++;                    // int64 high words all zero
        }
        if (big) atomicAdd(&sh_big, big);
        if (nz)  atomicAdd(&sh_nz, nz);
    }
    __syncthreads();
    const bool f32 = sh_big >= 8;
    const int  f64 = (sh_nz == 0) ? 1 : 0;

    for (int i = gt; i < NN; i += nthreads){ cnt[i] = 0; last_e64[i] = 0ULL; }
    if (gt == 0) *ovf_cnt = 0;

    if (blockIdx.x < 16){
        int fr = blockIdx.x * 256 + tid;                     // 0..4095
        int lane = fr & 63;
        int t    = (fr >> 6) & 3;
        int kc   = (fr >> 8) & 7;
        int ch   = fr >> 11;
        int col  = ch * 64 + t * 16 + (lane & 15);
        int kb   = kc * 32 + (lane >> 4) * 8;
        bf16x8 v;
        if (f32){
            const float* wg = (const float*)Wv + (size_t)col * INF + kb;
            #pragma unroll
            for (int j = 0; j < 8; ++j) v[j] = (short)f2bf_bits(wg[j]);
        } else {
            const ushort* wg = (const ushort*)Wv + (size_t)col * INF + kb;
            #pragma unroll
            for (int j = 0; j < 8; ++j) v[j] = (short)wg[j];
        }
        *(bf16x8*)(wbf + (size_t)fr * 8) = v;
    }

    grid.sync();

    // ---------------- phase 1: edges + GEMM ----------------
    for (int e = gt; e < EE; e += nthreads){
        int s = get_src(ei, e, f64);
        int d = get_dst(ei, e, f64);
        u64 pk = ((u64)(unsigned)(e + 1) << 16) | (unsigned)(d & 0xFFFF);
        int idx = atomicAdd(&cnt[s], 1);
        if (idx < CAP) slots[(size_t)s * CAP + idx] = pk;
        else {
            atomicMax(&last_e64[s], pk);    // rare: keeps le correct past CAP
            int o = atomicAdd(ovf_cnt, 1);
            if (o < OVF_CAP) ovf_list[o] = e;
        }
    }

    for (int bid = blockIdx.x; bid < GEMM_BLOCKS; bid += nb){
        const int lane = tid & 63;
        const int w    = tid >> 6;            // wave 0..3
        const int l15  = lane & 15;
        const int q    = lane >> 4;           // quad 0..3
        const int row0 = bid * 64 + w * 16;   // wave's 16 rows

        f32x4 acc[2][4];
        #pragma unroll
        for (int c = 0; c < 2; ++c)
            #pragma unroll
            for (int t = 0; t < 4; ++t) acc[c][t] = (f32x4){0.f, 0.f, 0.f, 0.f};

        if (f32){
            const float* xp = (const float*)xv_ + (size_t)(row0 + l15) * INF + q * 8;
            float4 c0 = ((const float4*)xp)[0];
            float4 c1 = ((const float4*)xp)[1];
            #pragma unroll
            for (int kc = 0; kc < 8; ++kc){
                float4 n0, n1;
                if (kc < 7){
                    const float4* p = (const float4*)(xp + (kc + 1) * 32);
                    n0 = p[0];
                    n1 = p[1];
                }
                bf16x8 afrag;
                afrag[0] = (short)f2bf_bits(c0.x); afrag[1] = (short)f2bf_bits(c0.y);
                afrag[2] = (short)f2bf_bits(c0.z); afrag[3] = (short)f2bf_bits(c0.w);
                afrag[4] = (short)f2bf_bits(c1.x); afrag[5] = (short)f2bf_bits(c1.y);
                afrag[6] = (short)f2bf_bits(c1.z); afrag[7] = (short)f2bf_bits(c1.w);
                #pragma unroll
                for (int c = 0; c < 2; ++c){
                    const ushort* wb = wbf + (size_t)c * 16384;
                    #pragma unroll
                    for (int t = 0; t < 4; ++t){
                        bf16x8 bfrag = *(const bf16x8*)(wb + (((size_t)kc * 4 + t) * 64 + lane) * 8);
                        acc[c][t] = __builtin_amdgcn_mfma_f32_16x16x32_bf16(afrag, bfrag, acc[c][t], 0, 0, 0);
                    }
                }
                if (kc < 7){ c0 = n0; c1 = n1; }
            }
        } else {
            const ushort* xp = (const ushort*)xv_ + (size_t)(row0 + l15) * INF + q * 8;
            bf16x8 af = *(const bf16x8*)xp;
            #pragma unroll
            for (int kc = 0; kc < 8; ++kc){
                bf16x8 nf;
                if (kc < 7) nf = *(const bf16x8*)(xp + (kc + 1) * 32);
                #pragma unroll
                for (int c = 0; c < 2; ++c){
                    const ushort* wb = wbf + (size_t)c * 16384;
                    #pragma unroll
                    for (int t = 0; t < 4; ++t){
                        bf16x8 bfrag = *(const bf16x8*)(wb + (((size_t)kc * 4 + t) * 64 + lane) * 8);
                        acc[c][t] = __builtin_amdgcn_mfma_f32_16x16x32_bf16(af, bfrag, acc[c][t], 0, 0, 0);
                    }
                }
                if (kc < 7) af = nf;
            }
        }

        // epilogue 1: h -> bf16, f-major [row][f*4+hd]; one 8B store
        #pragma unroll
        for (int r = 0; r < 4; ++r){
            int row = row0 + q * 4 + r;
            #pragma unroll
            for (int t = 0; t < 2; ++t){
                unsigned v0 = (unsigned)f2bf_bits(acc[0][t][r])
                            | ((unsigned)f2bf_bits(acc[0][t + 2][r]) << 16);  // heads 0,1
                unsigned v1 = (unsigned)f2bf_bits(acc[1][t][r])
                            | ((unsigned)f2bf_bits(acc[1][t + 2][r]) << 16);  // heads 2,3
                int f = t * 16 + l15;
                uint2 vv; vv.x = v0; vv.y = v1;
                *(uint2*)(h + (size_t)row * HF + f * 4) = vv;
            }
        }

        // epilogue 2: alpha dots from C registers
        float as_lo, as_hi, ad_lo, ad_hi;
        if (f32){
            const float* af = (const float*)av;
            as_lo = af[l15];        as_hi = af[16 + l15];
            ad_lo = af[OUTF + l15]; ad_hi = af[OUTF + 16 + l15];
        } else {
            const ushort* ab = (const ushort*)av;
            as_lo = bf2f(ab[l15]);        as_hi = bf2f(ab[16 + l15]);
            ad_lo = bf2f(ab[OUTF + l15]); ad_hi = bf2f(ab[OUTF + 16 + l15]);
        }
        #pragma unroll
        for (int r = 0; r < 4; ++r){
            int row = row0 + q * 4 + r;
            #pragma unroll
            for (int c = 0; c < 2; ++c){
                #pragma unroll
                for (int hp = 0; hp < 2; ++hp){
                    int t0 = hp * 2, t1 = hp * 2 + 1;
                    float ps = acc[c][t0][r] * as_lo + acc[c][t1][r] * as_hi;
                    float pd = acc[c][t0][r] * ad_lo + acc[c][t1][r] * ad_hi;
                    ps += __shfl_down(ps, 8, 16); pd += __shfl_down(pd, 8, 16);
                    ps += __shfl_down(ps, 4, 16); pd += __shfl_down(pd, 4, 16);
                    ps += __shfl_down(ps, 2, 16); pd += __shfl_down(pd, 2, 16);
                    ps += __shfl_down(ps, 1, 16); pd += __shfl_down(pd, 1, 16);
                    if (l15 == 0){
                        size_t o = (size_t)row * NH + c * 2 + hp;
                        alpha_s[o] = ps;
                        alpha_d[o] = pd;
                    }
                }
            }
        }
    }

    grid.sync();

    // ---------------- phase 2: softmax + aggregate ----------------
    const int M = *ovf_cnt;     // final after sync; uniform across grid
    {
        int lane = tid & 63;
        int wid  = (blockIdx.x * 256 + tid) >> 6;
        int nw   = nthreads >> 6;
        int b = lane >> 5;
        int f = lane & 31;
        int c  = lane & 7;      // softmax work item: bb = c>>2, hh = c&3
        int bb = c >> 2;
        int hh = c & 3;
        for (int n = wid; n < NN; n += nw){
            int m = cnt[n]; if (m > CAP) m = CAP;
            u64 le = last_e64[n];                 // 0 unless overflow happened

            const u64* sl = slots + (size_t)n * CAP;
            const ushort* hb = h + (size_t)b * NN * HF + f * 4;
            float ax = 0.f, ay = 0.f, az = 0.f, aww = 0.f;
            int i = 0;
            for (; i + 4 <= m; i += 4){
                ulonglong2 p0 = *(const ulonglong2*)(sl + i);       // uniform 16B
                ulonglong2 p1 = *(const ulonglong2*)(sl + i + 2);
                le = p0.x > le ? p0.x : le;  le = p0.y > le ? p0.y : le;
                le = p1.x > le ? p1.x : le;  le = p1.y > le ? p1.y : le;
                int d0 = (int)(p0.x & 0xFFFFULL);
                int d1 = (int)(p0.y & 0xFFFFULL);
                int d2 = (int)(p1.x & 0xFFFFULL);
                int d3 = (int)(p1.y & 0xFFFFULL);
                ushort4 u0 = *(const ushort4*)(hb + (size_t)d0 * HF);
                ushort4 u1 = *(const ushort4*)(hb + (size_t)d1 * HF);
                ushort4 u2 = *(const ushort4*)(hb + (size_t)d2 * HF);
                ushort4 u3 = *(const ushort4*)(hb + (size_t)d3 * HF);
                ax += bf2f(u0.x) + bf2f(u1.x) + bf2f(u2.x) + bf2f(u3.x);
                ay += bf2f(u0.y) + bf2f(u1.y) + bf2f(u2.y) + bf2f(u3.y);
                az += bf2f(u0.z) + bf2f(u1.z) + bf2f(u2.z) + bf2f(u3.z);
                aww += bf2f(u0.w) + bf2f(u1.w) + bf2f(u2.w) + bf2f(u3.w);
            }
            for (; i < m; ++i){
                u64 pk = sl[i];
                le = pk > le ? pk : le;
                int d = (int)(pk & 0xFFFFULL);
                ushort4 u = *(const ushort4*)(hb + (size_t)d * HF);
                ax += bf2f(u.x); ay += bf2f(u.y); az += bf2f(u.z); aww += bf2f(u.w);
            }

            // per-(bb,hh) attention weight (replicated x8 across the wave)
            float my_aw = 0.f;
            if (le != 0ULL){
                int d = (int)(le & 0xFFFFULL);      // dst of last edge: free!
                float ss = alpha_s[((size_t)bb * NN + n) * NH + hh]
                         + alpha_d[((size_t)bb * NN + d) * NH + hh];
                float so = alpha_s[((size_t)(1 - bb) * NN + n) * NH + hh]
                         + alpha_d[((size_t)(1 - bb) * NN + d) * NH + hh];
                ss = ss > 0.f ? ss : NEG_SLOPE * ss;
                so = so > 0.f ? so : NEG_SLOPE * so;
                float mx = fmaxf(ss, so);
                float e0 = __expf(ss - mx);
                float e1 = __expf(so - mx);
                my_aw = 0.25f * e0 / (e0 + e1);
            }
            if (lane < 8) aw[((size_t)bb * NN + n) * NH + hh] = my_aw;  // for fix

            float aw0 = __shfl(my_aw, (b << 2) + 0, 8);
            float aw1 = __shfl(my_aw, (b << 2) + 1, 8);
            float aw2 = __shfl(my_aw, (b << 2) + 2, 8);
            float aw3 = __shfl(my_aw, (b << 2) + 3, 8);

            out_f[((size_t)b * NN + n) * OUTF + f] =
                aw0 * ax + aw1 * ay + aw2 * az + aw3 * aww;
        }
    }

    // ---------------- phase 3: overflow fix (uniformly skipped) ----------------
    if (M != 0){
        grid.sync();
        int Mc = M > OVF_CAP ? OVF_CAP : M;
        int lane = tid & 63;
        int wid  = (blockIdx.x * 256 + tid) >> 6;
        int nw   = nthreads >> 6;
        int b = lane >> 5;
        int f = lane & 31;
        for (int i = wid; i < Mc; i += nw){
            int e = ovf_list[i];
            int s = get_src(ei, e, f64);
            int d = get_dst(ei, e, f64);
            float4 awv = *(const float4*)(aw + ((size_t)b * NN + s) * NH);
            ushort4 u = *(const ushort4*)(h + ((size_t)b * NN + d) * HF + f * 4);
            float a2 = awv.x * bf2f(u.x) + awv.y * bf2f(u.y)
                     + awv.z * bf2f(u.z) + awv.w * bf2f(u.w);
            atomicAdd(&out_f[((size_t)b * NN + s) * OUTF + f], a2);
        }
    }
}

// ============================================================================
// FALLBACK pipeline (round-3 verified, byte-identical behavior) — used only if
// cooperative launch is unavailable/rejected.
// ============================================================================
__global__ void k_init(const ushort* __restrict__ xr, const int* __restrict__ er,
                       const void* __restrict__ Wv,
                       int* __restrict__ flags, ushort* __restrict__ wbf,
                       int* __restrict__ cnt, int* __restrict__ last_e,
                       int* __restrict__ ovf_cnt){
    int i = blockIdx.x * blockDim.x + threadIdx.x;
    if (i < NN){ cnt[i] = 0; last_e[i] = -1; }
    if (i == 0) *ovf_cnt = 0;
    if (blockIdx.x < 16){
        __shared__ int cnt_big, cnt_nz;
        if (threadIdx.x == 0){ cnt_big = 0; cnt_nz = 0; }
        __syncthreads();
        int big = 0;
        for (int k = threadIdx.x; k < 8192; k += blockDim.x){
            unsigned e = ((unsigned)xr[2 * k] >> 7) & 0xff;
            if (e >= 0xC0) big++;
        }
        int nz = 0;
        for (int k = threadIdx.x; k < 4096; k += blockDim.x){
            if (er[2 * k + 1] != 0) nz++;
        }
        atomicAdd(&cnt_big, big);
        atomicAdd(&cnt_nz, nz);
        __syncthreads();
        if (blockIdx.x == 0 && threadIdx.x == 0){
            flags[0] = (cnt_big >= 16) ? 1 : 0;
            flags[1] = (cnt_nz == 0) ? 1 : 0;
        }
        const bool f32w = (cnt_big >= 16);
        int fr = blockIdx.x * 256 + threadIdx.x;
        {
            int lane = fr & 63;
            int t    = (fr >> 6) & 3;
            int kc   = (fr >> 8) & 7;
            int ch   = fr >> 11;
            int col  = ch * 64 + t * 16 + (lane & 15);
            int kb   = kc * 32 + (lane >> 4) * 8;
            bf16x8 v;
            if (f32w){
                const float* wg = (const float*)Wv + (size_t)col * INF + kb;
                #pragma unroll
                for (int j = 0; j < 8; ++j) v[j] = (short)f2bf_bits(wg[j]);
            } else {
                const ushort* wg = (const ushort*)Wv + (size_t)col * INF + kb;
                #pragma unroll
                for (int j = 0; j < 8; ++j) v[j] = (short)wg[j];
            }
            *(bf16x8*)(wbf + (size_t)fr * 8) = v;
        }
    }
}

__global__ __launch_bounds__(256, 2)
void k_gemm(const void* __restrict__ xv_, const ushort* __restrict__ wbf,
            const void* __restrict__ av, const int* __restrict__ ei,
            const int* __restrict__ flags, ushort* __restrict__ h,
            float* __restrict__ alpha_s, float* __restrict__ alpha_d,
            int* __restrict__ last_e, int* __restrict__ cnt,
            unsigned* __restrict__ slots, int* __restrict__ ovf_cnt,
            int* __restrict__ ovf_list){
    if (blockIdx.x < EDGE_BLOCKS){
        int f64 = flags[1];
        int e = blockIdx.x * 256 + threadIdx.x;
        if (e < EE){
            int s = get_src(ei, e, f64);
            int idx = atomicAdd(&cnt[s], 1);
            if (idx < CAP) slots[(size_t)s * CAP + idx] = (unsigned)e;
            else {
                atomicMax(&last_e[s], e);
                int o = atomicAdd(ovf_cnt, 1);
                if (o < OVF_CAP) ovf_list[o] = e;
            }
        }
        return;
    }

    const int bid  = blockIdx.x - EDGE_BLOCKS;
    const int tid  = threadIdx.x;
    const int lane = tid & 63;
    const int w    = tid >> 6;
    const int l15  = lane & 15;
    const int q    = lane >> 4;
    const bool f32 = flags[0] != 0;
    const int row0 = bid * 64 + w * 16;

    f32x4 acc[2][4];
    #pragma unroll
    for (int c = 0; c < 2; ++c)
        #pragma unroll
        for (int t = 0; t < 4; ++t) acc[c][t] = (f32x4){0.f, 0.f, 0.f, 0.f};

    if (f32){
        const float* xp = (const float*)xv_ + (size_t)(row0 + l15) * INF + q * 8;
        float4 c0 = ((const float4*)xp)[0];
        float4 c1 = ((const float4*)xp)[1];
        #pragma unroll
        for (int kc = 0; kc < 8; ++kc){
            float4 n0, n1;
            if (kc < 7){
                const float4* p = (const float4*)(xp + (kc + 1) * 32);
                n0 = p[0];
                n1 = p[1];
            }
            bf16x8 afrag;
            afrag[0] = (short)f2bf_bits(c0.x); afrag[1] = (short)f2bf_bits(c0.y);
            afrag[2] = (short)f2bf_bits(c0.z); afrag[3] = (short)f2bf_bits(c0.w);
            afrag[4] = (short)f2bf_bits(c1.x); afrag[5] = (short)f2bf_bits(c1.y);
            afrag[6] = (short)f2bf_bits(c1.z); afrag[7] = (short)f2bf_bits(c1.w);
            #pragma unroll
            for (int c = 0; c < 2; ++c){
                const ushort* wb = wbf + (size_t)c * 16384;
                #pragma unroll
                for (int t = 0; t < 4; ++t){
                    bf16x8 bfrag = *(const bf16x8*)(wb + (((size_t)kc * 4 + t) * 64 + lane) * 8);
                    acc[c][t] = __builtin_amdgcn_mfma_f32_16x16x32_bf16(afrag, bfrag, acc[c][t], 0, 0, 0);
                }
            }
            if (kc < 7){ c0 = n0; c1 = n1; }
        }
    } else {
        const ushort* xp = (const ushort*)xv_ + (size_t)(row0 + l15) * INF + q * 8;
        bf16x8 af = *(const bf16x8*)xp;
        #pragma unroll
        for (int kc = 0; kc < 8; ++kc){
            bf16x8 nf;
            if (kc < 7) nf = *(const bf16x8*)(xp + (kc + 1) * 32);
            #pragma unroll
            for (int c = 0; c < 2; ++c){
                const ushort* wb = wbf + (size_t)c * 16384;
                #pragma unroll
                for (int t = 0; t < 4; ++t){
                    bf16x8 bfrag = *(const bf16x8*)(wb + (((size_t)kc * 4 + t) * 64 + lane) * 8);
                    acc[c][t] = __builtin_amdgcn_mfma_f32_16x16x32_bf16(af, bfrag, acc[c][t], 0, 0, 0);
                }
            }
            if (kc < 7) af = nf;
        }
    }

    #pragma unroll
    for (int r = 0; r < 4; ++r){
        int row = row0 + q * 4 + r;
        #pragma unroll
        for (int t = 0; t < 2; ++t){
            unsigned v0 = (unsigned)f2bf_bits(acc[0][t][r])
                        | ((unsigned)f2bf_bits(acc[0][t + 2][r]) << 16);
            unsigned v1 = (unsigned)f2bf_bits(acc[1][t][r])
                        | ((unsigned)f2bf_bits(acc[1][t + 2][r]) << 16);
            int f = t * 16 + l15;
            uint2 vv; vv.x = v0; vv.y = v1;
            *(uint2*)(h + (size_t)row * HF + f * 4) = vv;
        }
    }

    float as_lo, as_hi, ad_lo, ad_hi;
    if (f32){
        const float* af = (const float*)av;
        as_lo = af[l15];        as_hi = af[16 + l15];
        ad_lo = af[OUTF + l15]; ad_hi = af[OUTF + 16 + l15];
    } else {
        const ushort* ab = (const ushort*)av;
        as_lo = bf2f(ab[l15]);        as_hi = bf2f(ab[16 + l15]);
        ad_lo = bf2f(ab[OUTF + l15]); ad_hi = bf2f(ab[OUTF + 16 + l15]);
    }
    #pragma unroll
    for (int r = 0; r < 4; ++r){
        int row = row0 + q * 4 + r;
        #pragma unroll
        for (int c = 0; c < 2; ++c){
            #pragma unroll
            for (int hp = 0; hp < 2; ++hp){
                int t0 = hp * 2, t1 = hp * 2 + 1;
                float ps = acc[c][t0][r] * as_lo + acc[c][t1][r] * as_hi;
                float pd = acc[c][t0][r] * ad_lo + acc[c][t1][r] * ad_hi;
                ps += __shfl_down(ps, 8, 16); pd += __shfl_down(pd, 8, 16);
                ps += __shfl_down(ps, 4, 16); pd += __shfl_down(pd, 4, 16);
                ps += __shfl_down(ps, 2, 16); pd += __shfl_down(pd, 2, 16);
                ps += __shfl_down(ps, 1, 16); pd += __shfl_down(pd, 1, 16);
                if (l15 == 0){
                    size_t o = (size_t)row * NH + c * 2 + hp;
                    alpha_s[o] = ps;
                    alpha_d[o] = pd;
                }
            }
        }
    }
}

__global__ __launch_bounds__(256)
void k_agg(const unsigned* __restrict__ slots, const int* __restrict__ cnt,
           const int* __restrict__ last_e, const int* __restrict__ ei,
           const int* __restrict__ flags,
           const float* __restrict__ alpha_s, const float* __restrict__ alpha_d,
           const ushort* __restrict__ h, float* __restrict__ aw,
           float* __restrict__ out_f){
    int lane = threadIdx.x & 63;
    int wid  = (blockIdx.x * blockDim.x + threadIdx.x) >> 6;
    int nw   = (gridDim.x * blockDim.x) >> 6;
    int b = lane >> 5;
    int f = lane & 31;
    int c  = lane & 7;
    int bb = c >> 2;
    int hh = c & 3;
    int f64 = flags[1];
    for (int n = wid; n < NN; n += nw){
        int m  = cnt[n]; if (m > CAP) m = CAP;
        int le = last_e[n];

        const unsigned* sl = slots + (size_t)n * CAP;
        const ushort* hb = h + (size_t)b * NN * HF + f * 4;
        float ax = 0.f, ay = 0.f, az = 0.f, aww = 0.f;
        int i = 0;
        for (; i + 4 <= m; i += 4){
            uint4 ee = *(const uint4*)(sl + i);
            le = max(le, (int)ee.x); le = max(le, (int)ee.y);
            le = max(le, (int)ee.z); le = max(le, (int)ee.w);
            int d0 = get_dst(ei, (int)ee.x, f64);
            int d1 = get_dst(ei, (int)ee.y, f64);
            int d2 = get_dst(ei, (int)ee.z, f64);
            int d3 = get_dst(ei, (int)ee.w, f64);
            ushort4 u0 = *(const ushort4*)(hb + (size_t)d0 * HF);
            ushort4 u1 = *(const ushort4*)(hb + (size_t)d1 * HF);
            ushort4 u2 = *(const ushort4*)(hb + (size_t)d2 * HF);
            ushort4 u3 = *(const ushort4*)(hb + (size_t)d3 * HF);
            ax += bf2f(u0.x) + bf2f(u1.x) + bf2f(u2.x) + bf2f(u3.x);
            ay += bf2f(u0.y) + bf2f(u1.y) + bf2f(u2.y) + bf2f(u3.y);
            az += bf2f(u0.z) + bf2f(u1.z) + bf2f(u2.z) + bf2f(u3.z);
            aww += bf2f(u0.w) + bf2f(u1.w) + bf2f(u2.w) + bf2f(u3.w);
        }
        for (; i < m; ++i){
            int e = (int)sl[i];
            le = max(le, e);
            int d = get_dst(ei, e, f64);
            ushort4 u = *(const ushort4*)(hb + (size_t)d * HF);
            ax += bf2f(u.x); ay += bf2f(u.y); az += bf2f(u.z); aww += bf2f(u.w);
        }

        float my_aw = 0.f;
        if (le >= 0){
            int d = get_dst(ei, le, f64);
            float ss = alpha_s[((size_t)bb * NN + n) * NH + hh]
                     + alpha_d[((size_t)bb * NN + d) * NH + hh];
            float so = alpha_s[((size_t)(1 - bb) * NN + n) * NH + hh]
                     + alpha_d[((size_t)(1 - bb) * NN + d) * NH + hh];
            ss = ss > 0.f ? ss : NEG_SLOPE * ss;
            so = so > 0.f ? so : NEG_SLOPE * so;
            float mx = fmaxf(ss, so);
            float e0 = __expf(ss - mx);
            float e1 = __expf(so - mx);
            my_aw = 0.25f * e0 / (e0 + e1);
        }
        if (lane < 8) aw[((size_t)bb * NN + n) * NH + hh] = my_aw;

        float aw0 = __shfl(my_aw, (b << 2) + 0, 8);
        float aw1 = __shfl(my_aw, (b << 2) + 1, 8);
        float aw2 = __shfl(my_aw, (b << 2) + 2, 8);
        float aw3 = __shfl(my_aw, (b << 2) + 3, 8);

        out_f[((size_t)b * NN + n) * OUTF + f] =
            aw0 * ax + aw1 * ay + aw2 * az + aw3 * aww;
    }
}

__global__ void k_fix(const int* __restrict__ ei, const int* __restrict__ flags,
                      const int* __restrict__ ovf_cnt, const int* __restrict__ ovf_list,
                      const ushort* __restrict__ h, const float* __restrict__ aw,
                      float* __restrict__ out_f){
    int lane = threadIdx.x & 63;
    int wid  = (blockIdx.x * blockDim.x + threadIdx.x) >> 6;
    int nw   = (gridDim.x * blockDim.x) >> 6;
    int b = lane >> 5;
    int f = lane & 31;
    int M = *ovf_cnt; if (M > OVF_CAP) M = OVF_CAP;
    int f64 = flags[1];
    for (int i = wid; i < M; i += nw){
        int e = ovf_list[i];
        int s = get_src(ei, e, f64);
        int d = get_dst(ei, e, f64);
        float4 awv = *(const float4*)(aw + ((size_t)b * NN + s) * NH);
        ushort4 u = *(const ushort4*)(h + ((size_t)b * NN + d) * HF + f * 4);
        float acc = awv.x * bf2f(u.x) + awv.y * bf2f(u.y)
                  + awv.z * bf2f(u.z) + awv.w * bf2f(u.w);
        atomicAdd(&out_f[((size_t)b * NN + s) * OUTF + f], acc);
    }
}

extern "C" void kernel_launch(void* const* d_in, const int* in_sizes, int n_in,
                              void* d_out, int out_size, void* d_ws, size_t ws_size,
                              hipStream_t stream){
    const void* x = d_in[0]; const void* eiv = d_in[1];
    const void* W = d_in[2]; const void* a  = d_in[3];
    for (int i = 0; i < n_in; ++i){
        if      (in_sizes[i] == BB * NN * INF) x   = d_in[i];
        else if (in_sizes[i] == 2 * EE)        eiv = d_in[i];
        else if (in_sizes[i] == HF * INF)      W   = d_in[i];
        else if (in_sizes[i] == 2 * OUTF)      a   = d_in[i];
    }
    const int* ei = (const int*)eiv;
    float* out = (float*)d_out;    // output dtype: float32 (verified)

    // Workspace (~20.2 MiB): flags | wbf | h | alpha_s | alpha_d | aw
    //                        | last_e64 | cnt | ovf_cnt | ovf_list | slots(u64)
    const size_t HN = (size_t)BB * NN * HF;
    char* p = (char*)d_ws;
    int*   flags    = (int*)p;                        p += 64;
    ushort* wbf     = (ushort*)p;                     p += 32768 * 2;
    ushort* h       = (ushort*)p;                     p += HN * 2;
    float* alpha_s  = (float*)p;                      p += (size_t)BB * NN * NH * 4;
    float* alpha_d  = (float*)p;                      p += (size_t)BB * NN * NH * 4;
    float* aw       = (float*)p;                      p += (size_t)BB * NN * NH * 4;
    u64*   last_e64 = (u64*)p;                        p += (size_t)NN * 8;
    int*   cnt      = (int*)p;                        p += (size_t)NN * 4;
    int*   ovf_cnt  = (int*)p;                        p += 64;
    int*   ovf_list = (int*)p;                        p += (size_t)OVF_CAP * 4;
    u64*   slots    = (u64*)p;

    static int coop_state = 0;   // 0 = unknown, 1 = cooperative ok, -1 = fallback
    static int coop_grid  = 1024;
    if (coop_state == 0){
        int dev = 0;
        hipGetDevice(&dev);
        hipDeviceProp_t prop{};
        int occ = 0;
        if (hipGetDeviceProperties(&prop, dev) == hipSuccess &&
            prop.cooperativeLaunch &&
            hipOccupancyMaxActiveBlocksPerMultiprocessor(&occ, k_fused, 256, 0) == hipSuccess &&
            occ > 0){
            long g = (long)occ * (long)prop.multiProcessorCount;
            if (g > 2048) g = 2048;
            if (g < 256)  g = 256;
            coop_grid  = (int)g;
            coop_state = 1;
        } else {
            coop_state = -1;
        }
    }

    if (coop_state == 1){
        void* ka[] = { (void*)&x, (void*)&ei, (void*)&W, (void*)&a,
                       (void*)&wbf, (void*)&h, (void*)&alpha_s, (void*)&alpha_d,
                       (void*)&last_e64, (void*)&cnt, (void*)&slots,
                       (void*)&ovf_cnt, (void*)&ovf_list, (void*)&aw, (void*)&out };
        hipError_t err = hipLaunchCooperativeKernel((void*)k_fused,
                                                    dim3(coop_grid), dim3(256),
                                                    ka, 0, stream);
        if (err == hipSuccess) return;
        coop_state = -1;   // fall through to the verified 4-launch pipeline
    }

    // ---- fallback: round-3 verified pipeline (uint slots fit in u64 region) ----
    k_init <<<(NN + 255) / 256, 256, 0, stream>>>((const ushort*)x, ei, W, flags, wbf,
                                                  cnt, (int*)last_e64, ovf_cnt);
    k_gemm <<<EDGE_BLOCKS + GEMM_BLOCKS, 256, 0, stream>>>(x, wbf, a, ei, flags, h,
                                                           alpha_s, alpha_d,
                                                           (int*)last_e64, cnt,
                                                           (unsigned*)slots, ovf_cnt,
                                                           ovf_list);
    k_agg  <<<2048, 256, 0, stream>>>((unsigned*)slots, cnt, (int*)last_e64, ei, flags,
                                      alpha_s, alpha_d, h, aw, out);
    k_fix  <<<32, 256, 0, stream>>>(ei, flags, ovf_cnt, ovf_list, h, aw, out);
}

// Round 5
// 243.913 us; speedup vs baseline: 1.3213x; 1.3213x over previous
//
#include <hip/hip_runtime.h>
#include <hip/hip_bf16.h>
#include <hip/hip_cooperative_groups.h>

namespace cg = cooperative_groups;

#define BB 2
#define NN 20000
#define EE 200000
#define INF 256
#define OUTF 32
#define NH 4
#define HF 128          // NH*OUTF
#define HF2 256         // 2*HF: node-major interleaved h row stride
#define NEG_SLOPE 0.2f
#define GEMM_BLOCKS 625  // 40000 rows / 64
#define EDGE_BLOCKS 782  // fallback path: ceil(200000/256)
#define CAP 48           // slots per node (deg ~ Poisson(10); overflow -> list)
#define OVF_CAP 8192

using bf16 = __hip_bfloat16;
typedef __attribute__((ext_vector_type(8))) short bf16x8;
typedef __attribute__((ext_vector_type(4))) float f32x4;
typedef unsigned long long u64;

__device__ __forceinline__ float bf2f(unsigned short s){ return __uint_as_float((unsigned)s << 16); }
__device__ __forceinline__ ushort f2bf_bits(float f){
    __hip_bfloat16 b = __float2bfloat16(f);
    return *(ushort*)&b;
}

__device__ __forceinline__ int get_src(const int* ei, int e, int f64){
    return f64 ? ei[2 * e] : ei[e];
}
__device__ __forceinline__ int get_dst(const int* ei, int e, int f64){
    return f64 ? ei[2 * EE + 2 * e] : ei[EE + e];
}

// h layout (both paths): [node][b][f*4+hd]  -> row stride HF2=256 ushorts (512B).
// Per edge, the agg wave (b=0: lanes 0-31, b=1: lanes 32-63) reads ONE contiguous
// 512B block.
__device__ __forceinline__ size_t hrow_of(int row){   // row = b*NN + n
    return (row >= NN) ? ((size_t)(row - NN) * 2 + 1) : ((size_t)row * 2);
}

// ============================================================================
// FUSED single-launch cooperative kernel.  __launch_bounds__(256,2): 128-VGPR
// budget — the verified no-spill config from rounds 2-3.  (Round 4's (256,4)
// capped VGPR at 64 -> scratch spill -> +54MB WRITE, 2.3x regression.)
// phase0: dtype detect + init cnt/last_e64 + wbf convert
// phase1: edge build (1 atomic/edge, packed u64 slot = ((e+1)<<16)|dst) + GEMM
// phase2: per-node softmax + atomic-free aggregate (dst directly from slot)
// phase3: overflow fix (uniformly skipped when ovf_cnt == 0)
// ============================================================================
__global__ __launch_bounds__(256, 2)
void k_fused(const void* __restrict__ xv_, const int* __restrict__ ei,
             const void* __restrict__ Wv, const void* __restrict__ av,
             ushort* __restrict__ wbf, ushort* __restrict__ h,
             float* __restrict__ alpha_s, float* __restrict__ alpha_d,
             u64* __restrict__ last_e64, int* __restrict__ cnt,
             u64* __restrict__ slots, int* __restrict__ ovf_cnt,
             int* __restrict__ ovf_list, float* __restrict__ aw,
             float* __restrict__ out_f)
{
    cg::grid_group grid = cg::this_grid();
    const int tid = threadIdx.x;
    const int nb  = gridDim.x;
    const int gt  = blockIdx.x * 256 + tid;
    const int nthreads = nb * 256;

    // ---------------- phase 0 ----------------
    __shared__ int sh_big, sh_nz;
    if (tid == 0){ sh_big = 0; sh_nz = 0; }
    __syncthreads();
    {
        const ushort* xr = (const ushort*)xv_;
        int big = 0;
        for (int k = tid; k < 2048; k += 256){
            unsigned e = ((unsigned)xr[2 * k] >> 7) & 0xff;  // bf16-exp of fp32 low half
            if (e >= 0xC0) big++;                            // impossible for N(0,1) bf16
        }
        int nz = 0;
        for (int k = tid; k < 1024; k += 256){
            if (ei[2 * k + 1] != 0) nz++;                    // int64 high words all zero
        }
        if (big) atomicAdd(&sh_big, big);
        if (nz)  atomicAdd(&sh_nz, nz);
    }
    __syncthreads();
    const bool f32 = sh_big >= 8;
    const int  f64 = (sh_nz == 0) ? 1 : 0;

    for (int i = gt; i < NN; i += nthreads){ cnt[i] = 0; last_e64[i] = 0ULL; }
    if (gt == 0) *ovf_cnt = 0;

    if (blockIdx.x < 16){
        int fr = blockIdx.x * 256 + tid;                     // 0..4095
        int lane = fr & 63;
        int t    = (fr >> 6) & 3;
        int kc   = (fr >> 8) & 7;
        int ch   = fr >> 11;
        int col  = ch * 64 + t * 16 + (lane & 15);
        int kb   = kc * 32 + (lane >> 4) * 8;
        bf16x8 v;
        if (f32){
            const float* wg = (const float*)Wv + (size_t)col * INF + kb;
            #pragma unroll
            for (int j = 0; j < 8; ++j) v[j] = (short)f2bf_bits(wg[j]);
        } else {
            const ushort* wg = (const ushort*)Wv + (size_t)col * INF + kb;
            #pragma unroll
            for (int j = 0; j < 8; ++j) v[j] = (short)wg[j];
        }
        *(bf16x8*)(wbf + (size_t)fr * 8) = v;
    }

    grid.sync();

    // ---------------- phase 1: edges + GEMM ----------------
    for (int e = gt; e < EE; e += nthreads){
        int s = get_src(ei, e, f64);
        int d = get_dst(ei, e, f64);
        u64 pk = ((u64)(unsigned)(e + 1) << 16) | (unsigned)(d & 0xFFFF);
        int idx = atomicAdd(&cnt[s], 1);
        if (idx < CAP) slots[(size_t)s * CAP + idx] = pk;
        else {
            atomicMax(&last_e64[s], pk);    // rare: keeps le correct past CAP
            int o = atomicAdd(ovf_cnt, 1);
            if (o < OVF_CAP) ovf_list[o] = e;
        }
    }

    for (int bid = blockIdx.x; bid < GEMM_BLOCKS; bid += nb){
        const int lane = tid & 63;
        const int w    = tid >> 6;            // wave 0..3
        const int l15  = lane & 15;
        const int q    = lane >> 4;           // quad 0..3
        const int row0 = bid * 64 + w * 16;   // wave's 16 rows

        f32x4 acc[2][4];
        #pragma unroll
        for (int c = 0; c < 2; ++c)
            #pragma unroll
            for (int t = 0; t < 4; ++t) acc[c][t] = (f32x4){0.f, 0.f, 0.f, 0.f};

        if (f32){
            const float* xp = (const float*)xv_ + (size_t)(row0 + l15) * INF + q * 8;
            float4 c0 = ((const float4*)xp)[0];
            float4 c1 = ((const float4*)xp)[1];
            #pragma unroll
            for (int kc = 0; kc < 8; ++kc){
                float4 n0, n1;
                if (kc < 7){
                    const float4* p = (const float4*)(xp + (kc + 1) * 32);
                    n0 = p[0];
                    n1 = p[1];
                }
                bf16x8 afrag;
                afrag[0] = (short)f2bf_bits(c0.x); afrag[1] = (short)f2bf_bits(c0.y);
                afrag[2] = (short)f2bf_bits(c0.z); afrag[3] = (short)f2bf_bits(c0.w);
                afrag[4] = (short)f2bf_bits(c1.x); afrag[5] = (short)f2bf_bits(c1.y);
                afrag[6] = (short)f2bf_bits(c1.z); afrag[7] = (short)f2bf_bits(c1.w);
                #pragma unroll
                for (int c = 0; c < 2; ++c){
                    const ushort* wb = wbf + (size_t)c * 16384;
                    #pragma unroll
                    for (int t = 0; t < 4; ++t){
                        bf16x8 bfrag = *(const bf16x8*)(wb + (((size_t)kc * 4 + t) * 64 + lane) * 8);
                        acc[c][t] = __builtin_amdgcn_mfma_f32_16x16x32_bf16(afrag, bfrag, acc[c][t], 0, 0, 0);
                    }
                }
                if (kc < 7){ c0 = n0; c1 = n1; }
            }
        } else {
            const ushort* xp = (const ushort*)xv_ + (size_t)(row0 + l15) * INF + q * 8;
            bf16x8 af = *(const bf16x8*)xp;
            #pragma unroll
            for (int kc = 0; kc < 8; ++kc){
                bf16x8 nf;
                if (kc < 7) nf = *(const bf16x8*)(xp + (kc + 1) * 32);
                #pragma unroll
                for (int c = 0; c < 2; ++c){
                    const ushort* wb = wbf + (size_t)c * 16384;
                    #pragma unroll
                    for (int t = 0; t < 4; ++t){
                        bf16x8 bfrag = *(const bf16x8*)(wb + (((size_t)kc * 4 + t) * 64 + lane) * 8);
                        acc[c][t] = __builtin_amdgcn_mfma_f32_16x16x32_bf16(af, bfrag, acc[c][t], 0, 0, 0);
                    }
                }
                if (kc < 7) af = nf;
            }
        }

        // epilogue 1: h -> bf16, node-major interleaved [n][b][f*4+hd]
        #pragma unroll
        for (int r = 0; r < 4; ++r){
            int row = row0 + q * 4 + r;
            ushort* hp_ = h + hrow_of(row) * HF;
            #pragma unroll
            for (int t = 0; t < 2; ++t){
                unsigned v0 = (unsigned)f2bf_bits(acc[0][t][r])
                            | ((unsigned)f2bf_bits(acc[0][t + 2][r]) << 16);  // heads 0,1
                unsigned v1 = (unsigned)f2bf_bits(acc[1][t][r])
                            | ((unsigned)f2bf_bits(acc[1][t + 2][r]) << 16);  // heads 2,3
                int f = t * 16 + l15;
                uint2 vv; vv.x = v0; vv.y = v1;
                *(uint2*)(hp_ + f * 4) = vv;
            }
        }

        // epilogue 2: alpha dots from C registers
        float as_lo, as_hi, ad_lo, ad_hi;
        if (f32){
            const float* af = (const float*)av;
            as_lo = af[l15];        as_hi = af[16 + l15];
            ad_lo = af[OUTF + l15]; ad_hi = af[OUTF + 16 + l15];
        } else {
            const ushort* ab = (const ushort*)av;
            as_lo = bf2f(ab[l15]);        as_hi = bf2f(ab[16 + l15]);
            ad_lo = bf2f(ab[OUTF + l15]); ad_hi = bf2f(ab[OUTF + 16 + l15]);
        }
        #pragma unroll
        for (int r = 0; r < 4; ++r){
            int row = row0 + q * 4 + r;
            #pragma unroll
            for (int c = 0; c < 2; ++c){
                #pragma unroll
                for (int hp = 0; hp < 2; ++hp){
                    int t0 = hp * 2, t1 = hp * 2 + 1;
                    float ps = acc[c][t0][r] * as_lo + acc[c][t1][r] * as_hi;
                    float pd = acc[c][t0][r] * ad_lo + acc[c][t1][r] * ad_hi;
                    ps += __shfl_down(ps, 8, 16); pd += __shfl_down(pd, 8, 16);
                    ps += __shfl_down(ps, 4, 16); pd += __shfl_down(pd, 4, 16);
                    ps += __shfl_down(ps, 2, 16); pd += __shfl_down(pd, 2, 16);
                    ps += __shfl_down(ps, 1, 16); pd += __shfl_down(pd, 1, 16);
                    if (l15 == 0){
                        size_t o = (size_t)row * NH + c * 2 + hp;
                        alpha_s[o] = ps;
                        alpha_d[o] = pd;
                    }
                }
            }
        }
    }

    grid.sync();

    // ---------------- phase 2: softmax + aggregate ----------------
    const int M = *ovf_cnt;     // final after sync; uniform across grid
    {
        int lane = tid & 63;
        int wid  = (blockIdx.x * 256 + tid) >> 6;
        int nw   = nthreads >> 6;
        int b = lane >> 5;
        int f = lane & 31;
        int c  = lane & 7;      // softmax work item: bb = c>>2, hh = c&3
        int bb = c >> 2;
        int hh = c & 3;
        const ushort* hb = h + b * HF + f * 4;   // + d*HF2 per gather (512B/edge contig)
        for (int n = wid; n < NN; n += nw){
            int m = cnt[n]; if (m > CAP) m = CAP;
            u64 le = last_e64[n];                 // 0 unless overflow happened

            const u64* sl = slots + (size_t)n * CAP;
            float ax = 0.f, ay = 0.f, az = 0.f, aww = 0.f;
            int i = 0;
            for (; i + 4 <= m; i += 4){
                ulonglong2 p0 = *(const ulonglong2*)(sl + i);       // uniform 16B
                ulonglong2 p1 = *(const ulonglong2*)(sl + i + 2);
                le = p0.x > le ? p0.x : le;  le = p0.y > le ? p0.y : le;
                le = p1.x > le ? p1.x : le;  le = p1.y > le ? p1.y : le;
                int d0 = (int)(p0.x & 0xFFFFULL);
                int d1 = (int)(p0.y & 0xFFFFULL);
                int d2 = (int)(p1.x & 0xFFFFULL);
                int d3 = (int)(p1.y & 0xFFFFULL);
                ushort4 u0 = *(const ushort4*)(hb + (size_t)d0 * HF2);
                ushort4 u1 = *(const ushort4*)(hb + (size_t)d1 * HF2);
                ushort4 u2 = *(const ushort4*)(hb + (size_t)d2 * HF2);
                ushort4 u3 = *(const ushort4*)(hb + (size_t)d3 * HF2);
                ax += bf2f(u0.x) + bf2f(u1.x) + bf2f(u2.x) + bf2f(u3.x);
                ay += bf2f(u0.y) + bf2f(u1.y) + bf2f(u2.y) + bf2f(u3.y);
                az += bf2f(u0.z) + bf2f(u1.z) + bf2f(u2.z) + bf2f(u3.z);
                aww += bf2f(u0.w) + bf2f(u1.w) + bf2f(u2.w) + bf2f(u3.w);
            }
            for (; i < m; ++i){
                u64 pk = sl[i];
                le = pk > le ? pk : le;
                int d = (int)(pk & 0xFFFFULL);
                ushort4 u = *(const ushort4*)(hb + (size_t)d * HF2);
                ax += bf2f(u.x); ay += bf2f(u.y); az += bf2f(u.z); aww += bf2f(u.w);
            }

            // per-(bb,hh) attention weight (replicated x8 across the wave)
            float my_aw = 0.f;
            if (le != 0ULL){
                int d = (int)(le & 0xFFFFULL);      // dst of last edge: free!
                float ss = alpha_s[((size_t)bb * NN + n) * NH + hh]
                         + alpha_d[((size_t)bb * NN + d) * NH + hh];
                float so = alpha_s[((size_t)(1 - bb) * NN + n) * NH + hh]
                         + alpha_d[((size_t)(1 - bb) * NN + d) * NH + hh];
                ss = ss > 0.f ? ss : NEG_SLOPE * ss;
                so = so > 0.f ? so : NEG_SLOPE * so;
                float mx = fmaxf(ss, so);
                float e0 = __expf(ss - mx);
                float e1 = __expf(so - mx);
                my_aw = 0.25f * e0 / (e0 + e1);
            }
            if (lane < 8) aw[((size_t)bb * NN + n) * NH + hh] = my_aw;  // for fix

            float aw0 = __shfl(my_aw, (b << 2) + 0, 8);
            float aw1 = __shfl(my_aw, (b << 2) + 1, 8);
            float aw2 = __shfl(my_aw, (b << 2) + 2, 8);
            float aw3 = __shfl(my_aw, (b << 2) + 3, 8);

            out_f[((size_t)b * NN + n) * OUTF + f] =
                aw0 * ax + aw1 * ay + aw2 * az + aw3 * aww;
        }
    }

    // ---------------- phase 3: overflow fix (uniformly skipped) ----------------
    if (M != 0){
        grid.sync();
        int Mc = M > OVF_CAP ? OVF_CAP : M;
        int lane = tid & 63;
        int wid  = (blockIdx.x * 256 + tid) >> 6;
        int nw   = nthreads >> 6;
        int b = lane >> 5;
        int f = lane & 31;
        for (int i = wid; i < Mc; i += nw){
            int e = ovf_list[i];
            int s = get_src(ei, e, f64);
            int d = get_dst(ei, e, f64);
            float4 awv = *(const float4*)(aw + ((size_t)b * NN + s) * NH);
            ushort4 u = *(const ushort4*)(h + ((size_t)d * 2 + b) * HF + f * 4);
            float a2 = awv.x * bf2f(u.x) + awv.y * bf2f(u.y)
                     + awv.z * bf2f(u.z) + awv.w * bf2f(u.w);
            atomicAdd(&out_f[((size_t)b * NN + s) * OUTF + f], a2);
        }
    }
}

// ============================================================================
// FALLBACK pipeline (round-3 verified structure, h layout updated to match) —
// used only if cooperative launch is unavailable/rejected.
// ============================================================================
__global__ void k_init(const ushort* __restrict__ xr, const int* __restrict__ er,
                       const void* __restrict__ Wv,
                       int* __restrict__ flags, ushort* __restrict__ wbf,
                       int* __restrict__ cnt, int* __restrict__ last_e,
                       int* __restrict__ ovf_cnt){
    int i = blockIdx.x * blockDim.x + threadIdx.x;
    if (i < NN){ cnt[i] = 0; last_e[i] = -1; }
    if (i == 0) *ovf_cnt = 0;
    if (blockIdx.x < 16){
        __shared__ int cnt_big, cnt_nz;
        if (threadIdx.x == 0){ cnt_big = 0; cnt_nz = 0; }
        __syncthreads();
        int big = 0;
        for (int k = threadIdx.x; k < 8192; k += blockDim.x){
            unsigned e = ((unsigned)xr[2 * k] >> 7) & 0xff;
            if (e >= 0xC0) big++;
        }
        int nz = 0;
        for (int k = threadIdx.x; k < 4096; k += blockDim.x){
            if (er[2 * k + 1] != 0) nz++;
        }
        atomicAdd(&cnt_big, big);
        atomicAdd(&cnt_nz, nz);
        __syncthreads();
        if (blockIdx.x == 0 && threadIdx.x == 0){
            flags[0] = (cnt_big >= 16) ? 1 : 0;
            flags[1] = (cnt_nz == 0) ? 1 : 0;
        }
        const bool f32w = (cnt_big >= 16);
        int fr = blockIdx.x * 256 + threadIdx.x;
        {
            int lane = fr & 63;
            int t    = (fr >> 6) & 3;
            int kc   = (fr >> 8) & 7;
            int ch   = fr >> 11;
            int col  = ch * 64 + t * 16 + (lane & 15);
            int kb   = kc * 32 + (lane >> 4) * 8;
            bf16x8 v;
            if (f32w){
                const float* wg = (const float*)Wv + (size_t)col * INF + kb;
                #pragma unroll
                for (int j = 0; j < 8; ++j) v[j] = (short)f2bf_bits(wg[j]);
            } else {
                const ushort* wg = (const ushort*)Wv + (size_t)col * INF + kb;
                #pragma unroll
                for (int j = 0; j < 8; ++j) v[j] = (short)wg[j];
            }
            *(bf16x8*)(wbf + (size_t)fr * 8) = v;
        }
    }
}

__global__ __launch_bounds__(256, 2)
void k_gemm(const void* __restrict__ xv_, const ushort* __restrict__ wbf,
            const void* __restrict__ av, const int* __restrict__ ei,
            const int* __restrict__ flags, ushort* __restrict__ h,
            float* __restrict__ alpha_s, float* __restrict__ alpha_d,
            int* __restrict__ last_e, int* __restrict__ cnt,
            unsigned* __restrict__ slots, int* __restrict__ ovf_cnt,
            int* __restrict__ ovf_list){
    if (blockIdx.x < EDGE_BLOCKS){
        int f64 = flags[1];
        int e = blockIdx.x * 256 + threadIdx.x;
        if (e < EE){
            int s = get_src(ei, e, f64);
            int idx = atomicAdd(&cnt[s], 1);
            if (idx < CAP) slots[(size_t)s * CAP + idx] = (unsigned)e;
            else {
                atomicMax(&last_e[s], e);
                int o = atomicAdd(ovf_cnt, 1);
                if (o < OVF_CAP) ovf_list[o] = e;
            }
        }
        return;
    }

    const int bid  = blockIdx.x - EDGE_BLOCKS;
    const int tid  = threadIdx.x;
    const int lane = tid & 63;
    const int w    = tid >> 6;
    const int l15  = lane & 15;
    const int q    = lane >> 4;
    const bool f32 = flags[0] != 0;
    const int row0 = bid * 64 + w * 16;

    f32x4 acc[2][4];
    #pragma unroll
    for (int c = 0; c < 2; ++c)
        #pragma unroll
        for (int t = 0; t < 4; ++t) acc[c][t] = (f32x4){0.f, 0.f, 0.f, 0.f};

    if (f32){
        const float* xp = (const float*)xv_ + (size_t)(row0 + l15) * INF + q * 8;
        float4 c0 = ((const float4*)xp)[0];
        float4 c1 = ((const float4*)xp)[1];
        #pragma unroll
        for (int kc = 0; kc < 8; ++kc){
            float4 n0, n1;
            if (kc < 7){
                const float4* p = (const float4*)(xp + (kc + 1) * 32);
                n0 = p[0];
                n1 = p[1];
            }
            bf16x8 afrag;
            afrag[0] = (short)f2bf_bits(c0.x); afrag[1] = (short)f2bf_bits(c0.y);
            afrag[2] = (short)f2bf_bits(c0.z); afrag[3] = (short)f2bf_bits(c0.w);
            afrag[4] = (short)f2bf_bits(c1.x); afrag[5] = (short)f2bf_bits(c1.y);
            afrag[6] = (short)f2bf_bits(c1.z); afrag[7] = (short)f2bf_bits(c1.w);
            #pragma unroll
            for (int c = 0; c < 2; ++c){
                const ushort* wb = wbf + (size_t)c * 16384;
                #pragma unroll
                for (int t = 0; t < 4; ++t){
                    bf16x8 bfrag = *(const bf16x8*)(wb + (((size_t)kc * 4 + t) * 64 + lane) * 8);
                    acc[c][t] = __builtin_amdgcn_mfma_f32_16x16x32_bf16(afrag, bfrag, acc[c][t], 0, 0, 0);
                }
            }
            if (kc < 7){ c0 = n0; c1 = n1; }
        }
    } else {
        const ushort* xp = (const ushort*)xv_ + (size_t)(row0 + l15) * INF + q * 8;
        bf16x8 af = *(const bf16x8*)xp;
        #pragma unroll
        for (int kc = 0; kc < 8; ++kc){
            bf16x8 nf;
            if (kc < 7) nf = *(const bf16x8*)(xp + (kc + 1) * 32);
            #pragma unroll
            for (int c = 0; c < 2; ++c){
                const ushort* wb = wbf + (size_t)c * 16384;
                #pragma unroll
                for (int t = 0; t < 4; ++t){
                    bf16x8 bfrag = *(const bf16x8*)(wb + (((size_t)kc * 4 + t) * 64 + lane) * 8);
                    acc[c][t] = __builtin_amdgcn_mfma_f32_16x16x32_bf16(af, bfrag, acc[c][t], 0, 0, 0);
                }
            }
            if (kc < 7) af = nf;
        }
    }

    #pragma unroll
    for (int r = 0; r < 4; ++r){
        int row = row0 + q * 4 + r;
        ushort* hp_ = h + hrow_of(row) * HF;
        #pragma unroll
        for (int t = 0; t < 2; ++t){
            unsigned v0 = (unsigned)f2bf_bits(acc[0][t][r])
                        | ((unsigned)f2bf_bits(acc[0][t + 2][r]) << 16);
            unsigned v1 = (unsigned)f2bf_bits(acc[1][t][r])
                        | ((unsigned)f2bf_bits(acc[1][t + 2][r]) << 16);
            int f = t * 16 + l15;
            uint2 vv; vv.x = v0; vv.y = v1;
            *(uint2*)(hp_ + f * 4) = vv;
        }
    }

    float as_lo, as_hi, ad_lo, ad_hi;
    if (f32){
        const float* af = (const float*)av;
        as_lo = af[l15];        as_hi = af[16 + l15];
        ad_lo = af[OUTF + l15]; ad_hi = af[OUTF + 16 + l15];
    } else {
        const ushort* ab = (const ushort*)av;
        as_lo = bf2f(ab[l15]);        as_hi = bf2f(ab[16 + l15]);
        ad_lo = bf2f(ab[OUTF + l15]); ad_hi = bf2f(ab[OUTF + 16 + l15]);
    }
    #pragma unroll
    for (int r = 0; r < 4; ++r){
        int row = row0 + q * 4 + r;
        #pragma unroll
        for (int c = 0; c < 2; ++c){
            #pragma unroll
            for (int hp = 0; hp < 2; ++hp){
                int t0 = hp * 2, t1 = hp * 2 + 1;
                float ps = acc[c][t0][r] * as_lo + acc[c][t1][r] * as_hi;
                float pd = acc[c][t0][r] * ad_lo + acc[c][t1][r] * ad_hi;
                ps += __shfl_down(ps, 8, 16); pd += __shfl_down(pd, 8, 16);
                ps += __shfl_down(ps, 4, 16); pd += __shfl_down(pd, 4, 16);
                ps += __shfl_down(ps, 2, 16); pd += __shfl_down(pd, 2, 16);
                ps += __shfl_down(ps, 1, 16); pd += __shfl_down(pd, 1, 16);
                if (l15 == 0){
                    size_t o = (size_t)row * NH + c * 2 + hp;
                    alpha_s[o] = ps;
                    alpha_d[o] = pd;
                }
            }
        }
    }
}

__global__ __launch_bounds__(256)
void k_agg(const unsigned* __restrict__ slots, const int* __restrict__ cnt,
           const int* __restrict__ last_e, const int* __restrict__ ei,
           const int* __restrict__ flags,
           const float* __restrict__ alpha_s, const float* __restrict__ alpha_d,
           const ushort* __restrict__ h, float* __restrict__ aw,
           float* __restrict__ out_f){
    int lane = threadIdx.x & 63;
    int wid  = (blockIdx.x * blockDim.x + threadIdx.x) >> 6;
    int nw   = (gridDim.x * blockDim.x) >> 6;
    int b = lane >> 5;
    int f = lane & 31;
    int c  = lane & 7;
    int bb = c >> 2;
    int hh = c & 3;
    int f64 = flags[1];
    const ushort* hb = h + b * HF + f * 4;
    for (int n = wid; n < NN; n += nw){
        int m  = cnt[n]; if (m > CAP) m = CAP;
        int le = last_e[n];

        const unsigned* sl = slots + (size_t)n * CAP;
        float ax = 0.f, ay = 0.f, az = 0.f, aww = 0.f;
        int i = 0;
        for (; i + 4 <= m; i += 4){
            uint4 ee = *(const uint4*)(sl + i);
            le = max(le, (int)ee.x); le = max(le, (int)ee.y);
            le = max(le, (int)ee.z); le = max(le, (int)ee.w);
            int d0 = get_dst(ei, (int)ee.x, f64);
            int d1 = get_dst(ei, (int)ee.y, f64);
            int d2 = get_dst(ei, (int)ee.z, f64);
            int d3 = get_dst(ei, (int)ee.w, f64);
            ushort4 u0 = *(const ushort4*)(hb + (size_t)d0 * HF2);
            ushort4 u1 = *(const ushort4*)(hb + (size_t)d1 * HF2);
            ushort4 u2 = *(const ushort4*)(hb + (size_t)d2 * HF2);
            ushort4 u3 = *(const ushort4*)(hb + (size_t)d3 * HF2);
            ax += bf2f(u0.x) + bf2f(u1.x) + bf2f(u2.x) + bf2f(u3.x);
            ay += bf2f(u0.y) + bf2f(u1.y) + bf2f(u2.y) + bf2f(u3.y);
            az += bf2f(u0.z) + bf2f(u1.z) + bf2f(u2.z) + bf2f(u3.z);
            aww += bf2f(u0.w) + bf2f(u1.w) + bf2f(u2.w) + bf2f(u3.w);
        }
        for (; i < m; ++i){
            int e = (int)sl[i];
            le = max(le, e);
            int d = get_dst(ei, e, f64);
            ushort4 u = *(const ushort4*)(hb + (size_t)d * HF2);
            ax += bf2f(u.x); ay += bf2f(u.y); az += bf2f(u.z); aww += bf2f(u.w);
        }

        float my_aw = 0.f;
        if (le >= 0){
            int d = get_dst(ei, le, f64);
            float ss = alpha_s[((size_t)bb * NN + n) * NH + hh]
                     + alpha_d[((size_t)bb * NN + d) * NH + hh];
            float so = alpha_s[((size_t)(1 - bb) * NN + n) * NH + hh]
                     + alpha_d[((size_t)(1 - bb) * NN + d) * NH + hh];
            ss = ss > 0.f ? ss : NEG_SLOPE * ss;
            so = so > 0.f ? so : NEG_SLOPE * so;
            float mx = fmaxf(ss, so);
            float e0 = __expf(ss - mx);
            float e1 = __expf(so - mx);
            my_aw = 0.25f * e0 / (e0 + e1);
        }
        if (lane < 8) aw[((size_t)bb * NN + n) * NH + hh] = my_aw;

        float aw0 = __shfl(my_aw, (b << 2) + 0, 8);
        float aw1 = __shfl(my_aw, (b << 2) + 1, 8);
        float aw2 = __shfl(my_aw, (b << 2) + 2, 8);
        float aw3 = __shfl(my_aw, (b << 2) + 3, 8);

        out_f[((size_t)b * NN + n) * OUTF + f] =
            aw0 * ax + aw1 * ay + aw2 * az + aw3 * aww;
    }
}

__global__ void k_fix(const int* __restrict__ ei, const int* __restrict__ flags,
                      const int* __restrict__ ovf_cnt, const int* __restrict__ ovf_list,
                      const ushort* __restrict__ h, const float* __restrict__ aw,
                      float* __restrict__ out_f){
    int lane = threadIdx.x & 63;
    int wid  = (blockIdx.x * blockDim.x + threadIdx.x) >> 6;
    int nw   = (gridDim.x * blockDim.x) >> 6;
    int b = lane >> 5;
    int f = lane & 31;
    int M = *ovf_cnt; if (M > OVF_CAP) M = OVF_CAP;
    int f64 = flags[1];
    for (int i = wid; i < M; i += nw){
        int e = ovf_list[i];
        int s = get_src(ei, e, f64);
        int d = get_dst(ei, e, f64);
        float4 awv = *(const float4*)(aw + ((size_t)b * NN + s) * NH);
        ushort4 u = *(const ushort4*)(h + ((size_t)d * 2 + b) * HF + f * 4);
        float acc = awv.x * bf2f(u.x) + awv.y * bf2f(u.y)
                  + awv.z * bf2f(u.z) + awv.w * bf2f(u.w);
        atomicAdd(&out_f[((size_t)b * NN + s) * OUTF + f], acc);
    }
}

extern "C" void kernel_launch(void* const* d_in, const int* in_sizes, int n_in,
                              void* d_out, int out_size, void* d_ws, size_t ws_size,
                              hipStream_t stream){
    const void* x = d_in[0]; const void* eiv = d_in[1];
    const void* W = d_in[2]; const void* a  = d_in[3];
    for (int i = 0; i < n_in; ++i){
        if      (in_sizes[i] == BB * NN * INF) x   = d_in[i];
        else if (in_sizes[i] == 2 * EE)        eiv = d_in[i];
        else if (in_sizes[i] == HF * INF)      W   = d_in[i];
        else if (in_sizes[i] == 2 * OUTF)      a   = d_in[i];
    }
    const int* ei = (const int*)eiv;
    float* out = (float*)d_out;    // output dtype: float32 (verified)

    // Workspace (~20.2 MiB): flags | wbf | h | alpha_s | alpha_d | aw
    //                        | last_e64 | cnt | ovf_cnt | ovf_list | slots(u64)
    const size_t HN = (size_t)BB * NN * HF;
    char* p = (char*)d_ws;
    int*   flags    = (int*)p;                        p += 64;
    ushort* wbf     = (ushort*)p;                     p += 32768 * 2;
    ushort* h       = (ushort*)p;                     p += HN * 2;
    float* alpha_s  = (float*)p;                      p += (size_t)BB * NN * NH * 4;
    float* alpha_d  = (float*)p;                      p += (size_t)BB * NN * NH * 4;
    float* aw       = (float*)p;                      p += (size_t)BB * NN * NH * 4;
    u64*   last_e64 = (u64*)p;                        p += (size_t)NN * 8;
    int*   cnt      = (int*)p;                        p += (size_t)NN * 4;
    int*   ovf_cnt  = (int*)p;                        p += 64;
    int*   ovf_list = (int*)p;                        p += (size_t)OVF_CAP * 4;
    u64*   slots    = (u64*)p;

    static int coop_state = 0;   // 0 = unknown, 1 = cooperative ok, -1 = fallback
    static int coop_grid  = 1024;
    if (coop_state == 0){
        int dev = 0;
        hipGetDevice(&dev);
        hipDeviceProp_t prop{};
        int occ = 0;
        if (hipGetDeviceProperties(&prop, dev) == hipSuccess &&
            prop.cooperativeLaunch &&
            hipOccupancyMaxActiveBlocksPerMultiprocessor(&occ, k_fused, 256, 0) == hipSuccess &&
            occ > 0){
            long g = (long)occ * (long)prop.multiProcessorCount;
            if (g > 2048) g = 2048;
            if (g < 256)  g = 256;
            coop_grid  = (int)g;
            coop_state = 1;
        } else {
            coop_state = -1;
        }
    }

    if (coop_state == 1){
        void* ka[] = { (void*)&x, (void*)&ei, (void*)&W, (void*)&a,
                       (void*)&wbf, (void*)&h, (void*)&alpha_s, (void*)&alpha_d,
                       (void*)&last_e64, (void*)&cnt, (void*)&slots,
                       (void*)&ovf_cnt, (void*)&ovf_list, (void*)&aw, (void*)&out };
        hipError_t err = hipLaunchCooperativeKernel((void*)k_fused,
                                                    dim3(coop_grid), dim3(256),
                                                    ka, 0, stream);
        if (err == hipSuccess) return;
        coop_state = -1;   // fall through to the verified 4-launch pipeline
    }

    // ---- fallback: round-3 verified pipeline (uint slots fit in u64 region) ----
    k_init <<<(NN + 255) / 256, 256, 0, stream>>>((const ushort*)x, ei, W, flags, wbf,
                                                  cnt, (int*)last_e64, ovf_cnt);
    k_gemm <<<EDGE_BLOCKS + GEMM_BLOCKS, 256, 0, stream>>>(x, wbf, a, ei, flags, h,
                                                           alpha_s, alpha_d,
                                                           (int*)last_e64, cnt,
                                                           (unsigned*)slots, ovf_cnt,
                                                           ovf_list);
    k_agg  <<<2048, 256, 0, stream>>>((unsigned*)slots, cnt, (int*)last_e64, ei, flags,
                                      alpha_s, alpha_d, h, aw, out);
    k_fix  <<<32, 256, 0, stream>>>(ei, flags, ovf_cnt, ovf_list, h, aw, out);
}

// Round 6
// 146.196 us; speedup vs baseline: 2.2045x; 1.6684x over previous
//
#include <hip/hip_runtime.h>
#include <hip/hip_bf16.h>

#define BB 2
#define NN 20000
#define EE 200000
#define INF 256
#define OUTF 32
#define NH 4
#define HF 128          // NH*OUTF
#define HF2 256         // 2*HF: node-major interleaved h row stride (ushorts)
#define NEG_SLOPE 0.2f
#define GEMM_BLOCKS 625  // 40000 rows / 64
#define EDGE_BLOCKS 782  // ceil(200000/256), 1 edge per thread
#define CAP 48           // u64 slots per node (deg ~ Poisson(10); overflow -> list)
#define OVF_CAP 8192

using bf16 = __hip_bfloat16;
typedef __attribute__((ext_vector_type(8))) short bf16x8;
typedef __attribute__((ext_vector_type(4))) float f32x4;
typedef unsigned long long u64;

__device__ __forceinline__ float bf2f(unsigned short s){ return __uint_as_float((unsigned)s << 16); }
__device__ __forceinline__ ushort f2bf_bits(float f){
    __hip_bfloat16 b = __float2bfloat16(f);
    return *(ushort*)&b;
}

__device__ __forceinline__ int get_src(const int* ei, int e, int f64){
    return f64 ? ei[2 * e] : ei[e];
}
__device__ __forceinline__ int get_dst(const int* ei, int e, int f64){
    return f64 ? ei[2 * EE + 2 * e] : ei[EE + e];
}

// h layout: [node][b][f*4+hd] -> row stride HF2=256 ushorts (512B). Per edge,
// the agg wave (b=0: lanes 0-31, b=1: lanes 32-63) reads ONE contiguous 512B.
__device__ __forceinline__ size_t hrow_of(int row){   // row = b*NN + n
    return (row >= NN) ? ((size_t)(row - NN) * 2 + 1) : ((size_t)row * 2);
}

// K0: init cnt/last_e64/ovf; blocks 0..15: dtype-detect (each block re-derives
// the flag deterministically) + W -> bf16 B-frag-linear wbf.
__global__ void k_init(const ushort* __restrict__ xr, const int* __restrict__ er,
                       const void* __restrict__ Wv,
                       int* __restrict__ flags, ushort* __restrict__ wbf,
                       int* __restrict__ cnt, u64* __restrict__ last_e64,
                       int* __restrict__ ovf_cnt){
    int i = blockIdx.x * blockDim.x + threadIdx.x;
    if (i < NN){ cnt[i] = 0; last_e64[i] = 0ULL; }
    if (i == 0) *ovf_cnt = 0;
    if (blockIdx.x < 16){
        __shared__ int cnt_big, cnt_nz;
        if (threadIdx.x == 0){ cnt_big = 0; cnt_nz = 0; }
        __syncthreads();
        int big = 0;
        for (int k = threadIdx.x; k < 8192; k += blockDim.x){
            unsigned e = ((unsigned)xr[2 * k] >> 7) & 0xff;   // bf16-exp of fp32 low half
            if (e >= 0xC0) big++;                              // impossible for N(0,1) bf16
        }
        int nz = 0;
        for (int k = threadIdx.x; k < 4096; k += blockDim.x){
            if (er[2 * k + 1] != 0) nz++;                      // int64 high words all zero
        }
        atomicAdd(&cnt_big, big);
        atomicAdd(&cnt_nz, nz);
        __syncthreads();
        if (blockIdx.x == 0 && threadIdx.x == 0){
            flags[0] = (cnt_big >= 16) ? 1 : 0;
            flags[1] = (cnt_nz == 0) ? 1 : 0;
        }
        const bool f32w = (cnt_big >= 16);
        int fr = blockIdx.x * 256 + threadIdx.x;               // 0..4095
        {
            int lane = fr & 63;
            int t    = (fr >> 6) & 3;
            int kc   = (fr >> 8) & 7;
            int ch   = fr >> 11;
            int col  = ch * 64 + t * 16 + (lane & 15);
            int kb   = kc * 32 + (lane >> 4) * 8;
            bf16x8 v;
            if (f32w){
                const float* wg = (const float*)Wv + (size_t)col * INF + kb;
                #pragma unroll
                for (int j = 0; j < 8; ++j) v[j] = (short)f2bf_bits(wg[j]);
            } else {
                const ushort* wg = (const ushort*)Wv + (size_t)col * INF + kb;
                #pragma unroll
                for (int j = 0; j < 8; ++j) v[j] = (short)wg[j];
            }
            *(bf16x8*)(wbf + (size_t)fr * 8) = v;
        }
    }
}

// K1: edge build, SEPARATE dispatch for profiler attribution.
// One atomic per edge; slot stores packed ((e+1)<<16)|dst so k_agg needs no ei
// gather and last_e = running max of packed values (dst comes free).
__global__ __launch_bounds__(256)
void k_edge(const int* __restrict__ ei, const int* __restrict__ flags,
            int* __restrict__ cnt, u64* __restrict__ slots,
            u64* __restrict__ last_e64, int* __restrict__ ovf_cnt,
            int* __restrict__ ovf_list){
    int f64 = flags[1];
    int e = blockIdx.x * 256 + threadIdx.x;
    if (e < EE){
        int s = get_src(ei, e, f64);
        int d = get_dst(ei, e, f64);
        u64 pk = ((u64)(unsigned)(e + 1) << 16) | (unsigned)(d & 0xFFFF);
        int idx = atomicAdd(&cnt[s], 1);
        if (idx < CAP) slots[(size_t)s * CAP + idx] = pk;
        else {
            atomicMax(&last_e64[s], pk);    // rare: keeps le correct past CAP
            int o = atomicAdd(ovf_cnt, 1);
            if (o < OVF_CAP) ovf_list[o] = e;
        }
    }
}

// K2: pure MFMA GEMM. One wave = 16 rows x BOTH col-halves; 1-deep x pipeline;
// h stored node-major interleaved.
__global__ __launch_bounds__(256, 2)
void k_gemm(const void* __restrict__ xv_, const ushort* __restrict__ wbf,
            const void* __restrict__ av, const int* __restrict__ flags,
            ushort* __restrict__ h,
            float* __restrict__ alpha_s, float* __restrict__ alpha_d){
    const int bid  = blockIdx.x;
    const int tid  = threadIdx.x;
    const int lane = tid & 63;
    const int w    = tid >> 6;            // wave 0..3
    const int l15  = lane & 15;
    const int q    = lane >> 4;           // quad 0..3
    const bool f32 = flags[0] != 0;

    const int row0 = bid * 64 + w * 16;   // wave's 16 rows

    f32x4 acc[2][4];
    #pragma unroll
    for (int c = 0; c < 2; ++c)
        #pragma unroll
        for (int t = 0; t < 4; ++t) acc[c][t] = (f32x4){0.f, 0.f, 0.f, 0.f};

    if (f32){
        const float* xp = (const float*)xv_ + (size_t)(row0 + l15) * INF + q * 8;
        float4 c0 = ((const float4*)xp)[0];
        float4 c1 = ((const float4*)xp)[1];
        #pragma unroll
        for (int kc = 0; kc < 8; ++kc){
            float4 n0, n1;
            if (kc < 7){
                const float4* p = (const float4*)(xp + (kc + 1) * 32);
                n0 = p[0];
                n1 = p[1];
            }
            bf16x8 afrag;
            afrag[0] = (short)f2bf_bits(c0.x); afrag[1] = (short)f2bf_bits(c0.y);
            afrag[2] = (short)f2bf_bits(c0.z); afrag[3] = (short)f2bf_bits(c0.w);
            afrag[4] = (short)f2bf_bits(c1.x); afrag[5] = (short)f2bf_bits(c1.y);
            afrag[6] = (short)f2bf_bits(c1.z); afrag[7] = (short)f2bf_bits(c1.w);
            #pragma unroll
            for (int c = 0; c < 2; ++c){
                const ushort* wb = wbf + (size_t)c * 16384;
                #pragma unroll
                for (int t = 0; t < 4; ++t){
                    bf16x8 bfrag = *(const bf16x8*)(wb + (((size_t)kc * 4 + t) * 64 + lane) * 8);
                    acc[c][t] = __builtin_amdgcn_mfma_f32_16x16x32_bf16(afrag, bfrag, acc[c][t], 0, 0, 0);
                }
            }
            if (kc < 7){ c0 = n0; c1 = n1; }
        }
    } else {
        const ushort* xp = (const ushort*)xv_ + (size_t)(row0 + l15) * INF + q * 8;
        bf16x8 af = *(const bf16x8*)xp;
        #pragma unroll
        for (int kc = 0; kc < 8; ++kc){
            bf16x8 nf;
            if (kc < 7) nf = *(const bf16x8*)(xp + (kc + 1) * 32);
            #pragma unroll
            for (int c = 0; c < 2; ++c){
                const ushort* wb = wbf + (size_t)c * 16384;
                #pragma unroll
                for (int t = 0; t < 4; ++t){
                    bf16x8 bfrag = *(const bf16x8*)(wb + (((size_t)kc * 4 + t) * 64 + lane) * 8);
                    acc[c][t] = __builtin_amdgcn_mfma_f32_16x16x32_bf16(af, bfrag, acc[c][t], 0, 0, 0);
                }
            }
            if (kc < 7) af = nf;
        }
    }

    // ---- epilogue 1: h -> bf16, node-major interleaved [n][b][f*4+hd] ----
    #pragma unroll
    for (int r = 0; r < 4; ++r){
        int row = row0 + q * 4 + r;
        ushort* hp_ = h + hrow_of(row) * HF;
        #pragma unroll
        for (int t = 0; t < 2; ++t){    // t = f-half; f = t*16 + l15
            unsigned v0 = (unsigned)f2bf_bits(acc[0][t][r])
                        | ((unsigned)f2bf_bits(acc[0][t + 2][r]) << 16);  // heads 0,1
            unsigned v1 = (unsigned)f2bf_bits(acc[1][t][r])
                        | ((unsigned)f2bf_bits(acc[1][t + 2][r]) << 16);  // heads 2,3
            int f = t * 16 + l15;
            uint2 vv; vv.x = v0; vv.y = v1;
            *(uint2*)(hp_ + f * 4) = vv;
        }
    }

    // ---- epilogue 2: alpha dots from C registers ----
    float as_lo, as_hi, ad_lo, ad_hi;
    if (f32){
        const float* af = (const float*)av;
        as_lo = af[l15];        as_hi = af[16 + l15];
        ad_lo = af[OUTF + l15]; ad_hi = af[OUTF + 16 + l15];
    } else {
        const ushort* ab = (const ushort*)av;
        as_lo = bf2f(ab[l15]);        as_hi = bf2f(ab[16 + l15]);
        ad_lo = bf2f(ab[OUTF + l15]); ad_hi = bf2f(ab[OUTF + 16 + l15]);
    }
    #pragma unroll
    for (int r = 0; r < 4; ++r){
        int row = row0 + q * 4 + r;
        #pragma unroll
        for (int c = 0; c < 2; ++c){
            #pragma unroll
            for (int hp = 0; hp < 2; ++hp){
                int t0 = hp * 2, t1 = hp * 2 + 1;
                float ps = acc[c][t0][r] * as_lo + acc[c][t1][r] * as_hi;
                float pd = acc[c][t0][r] * ad_lo + acc[c][t1][r] * ad_hi;
                ps += __shfl_down(ps, 8, 16); pd += __shfl_down(pd, 8, 16);
                ps += __shfl_down(ps, 4, 16); pd += __shfl_down(pd, 4, 16);
                ps += __shfl_down(ps, 2, 16); pd += __shfl_down(pd, 2, 16);
                ps += __shfl_down(ps, 1, 16); pd += __shfl_down(pd, 1, 16);
                if (l15 == 0){
                    size_t o = (size_t)row * NH + c * 2 + hp;
                    alpha_s[o] = ps;
                    alpha_d[o] = pd;
                }
            }
        }
    }
}

// K3 (fused aw+agg): one wave per node. Bucket walk reads packed u64 slots:
// dst = pk & 0xFFFF (no ei gather), le = running max (dst of last edge free).
// Per edge: ONE contiguous 512B wave read from interleaved h.
__global__ __launch_bounds__(256)
void k_agg(const u64* __restrict__ slots, const int* __restrict__ cnt,
           const u64* __restrict__ last_e64,
           const float* __restrict__ alpha_s, const float* __restrict__ alpha_d,
           const ushort* __restrict__ h, float* __restrict__ aw,
           float* __restrict__ out_f){
    int lane = threadIdx.x & 63;
    int wid  = (blockIdx.x * blockDim.x + threadIdx.x) >> 6;
    int nw   = (gridDim.x * blockDim.x) >> 6;
    int b = lane >> 5;
    int f = lane & 31;
    int c  = lane & 7;          // softmax work item: bb = c>>2, hh = c&3
    int bb = c >> 2;
    int hh = c & 3;
    const ushort* hb = h + b * HF + f * 4;   // + d*HF2 per gather
    for (int n = wid; n < NN; n += nw){
        int m = cnt[n]; if (m > CAP) m = CAP;
        u64 le = last_e64[n];                 // 0 unless overflow happened

        const u64* sl = slots + (size_t)n * CAP;
        float ax = 0.f, ay = 0.f, az = 0.f, aww = 0.f;
        int i = 0;
        for (; i + 4 <= m; i += 4){
            ulonglong2 p0 = *(const ulonglong2*)(sl + i);       // uniform 16B
            ulonglong2 p1 = *(const ulonglong2*)(sl + i + 2);
            le = p0.x > le ? p0.x : le;  le = p0.y > le ? p0.y : le;
            le = p1.x > le ? p1.x : le;  le = p1.y > le ? p1.y : le;
            int d0 = (int)(p0.x & 0xFFFFULL);
            int d1 = (int)(p0.y & 0xFFFFULL);
            int d2 = (int)(p1.x & 0xFFFFULL);
            int d3 = (int)(p1.y & 0xFFFFULL);
            ushort4 u0 = *(const ushort4*)(hb + (size_t)d0 * HF2);
            ushort4 u1 = *(const ushort4*)(hb + (size_t)d1 * HF2);
            ushort4 u2 = *(const ushort4*)(hb + (size_t)d2 * HF2);
            ushort4 u3 = *(const ushort4*)(hb + (size_t)d3 * HF2);
            ax += bf2f(u0.x) + bf2f(u1.x) + bf2f(u2.x) + bf2f(u3.x);
            ay += bf2f(u0.y) + bf2f(u1.y) + bf2f(u2.y) + bf2f(u3.y);
            az += bf2f(u0.z) + bf2f(u1.z) + bf2f(u2.z) + bf2f(u3.z);
            aww += bf2f(u0.w) + bf2f(u1.w) + bf2f(u2.w) + bf2f(u3.w);
        }
        for (; i < m; ++i){
            u64 pk = sl[i];
            le = pk > le ? pk : le;
            int d = (int)(pk & 0xFFFFULL);
            ushort4 u = *(const ushort4*)(hb + (size_t)d * HF2);
            ax += bf2f(u.x); ay += bf2f(u.y); az += bf2f(u.z); aww += bf2f(u.w);
        }

        // per-(bb,hh) attention weight (replicated x8 across the wave)
        float my_aw = 0.f;
        if (le != 0ULL){
            int d = (int)(le & 0xFFFFULL);      // dst of last edge: free
            float ss = alpha_s[((size_t)bb * NN + n) * NH + hh]
                     + alpha_d[((size_t)bb * NN + d) * NH + hh];
            float so = alpha_s[((size_t)(1 - bb) * NN + n) * NH + hh]
                     + alpha_d[((size_t)(1 - bb) * NN + d) * NH + hh];
            ss = ss > 0.f ? ss : NEG_SLOPE * ss;
            so = so > 0.f ? so : NEG_SLOPE * so;
            float mx = fmaxf(ss, so);
            float e0 = __expf(ss - mx);
            float e1 = __expf(so - mx);
            my_aw = 0.25f * e0 / (e0 + e1);
        }
        if (lane < 8) aw[((size_t)bb * NN + n) * NH + hh] = my_aw;  // for k_fix

        float aw0 = __shfl(my_aw, (b << 2) + 0, 8);
        float aw1 = __shfl(my_aw, (b << 2) + 1, 8);
        float aw2 = __shfl(my_aw, (b << 2) + 2, 8);
        float aw3 = __shfl(my_aw, (b << 2) + 3, 8);

        out_f[((size_t)b * NN + n) * OUTF + f] =
            aw0 * ax + aw1 * ay + aw2 * az + aw3 * aww;
    }
}

// K4: overflow fix-up (normally empty). One wave per overflow edge, atomics.
__global__ void k_fix(const int* __restrict__ ei, const int* __restrict__ flags,
                      const int* __restrict__ ovf_cnt, const int* __restrict__ ovf_list,
                      const ushort* __restrict__ h, const float* __restrict__ aw,
                      float* __restrict__ out_f){
    int lane = threadIdx.x & 63;
    int wid  = (blockIdx.x * blockDim.x + threadIdx.x) >> 6;
    int nw   = (gridDim.x * blockDim.x) >> 6;
    int b = lane >> 5;
    int f = lane & 31;
    int M = *ovf_cnt; if (M > OVF_CAP) M = OVF_CAP;
    int f64 = flags[1];
    for (int i = wid; i < M; i += nw){
        int e = ovf_list[i];
        int s = get_src(ei, e, f64);
        int d = get_dst(ei, e, f64);
        float4 awv = *(const float4*)(aw + ((size_t)b * NN + s) * NH);
        ushort4 u = *(const ushort4*)(h + ((size_t)d * 2 + b) * HF + f * 4);
        float acc = awv.x * bf2f(u.x) + awv.y * bf2f(u.y)
                  + awv.z * bf2f(u.z) + awv.w * bf2f(u.w);
        atomicAdd(&out_f[((size_t)b * NN + s) * OUTF + f], acc);
    }
}

extern "C" void kernel_launch(void* const* d_in, const int* in_sizes, int n_in,
                              void* d_out, int out_size, void* d_ws, size_t ws_size,
                              hipStream_t stream){
    const void* x = d_in[0]; const void* eiv = d_in[1];
    const void* W = d_in[2]; const void* a  = d_in[3];
    for (int i = 0; i < n_in; ++i){
        if      (in_sizes[i] == BB * NN * INF) x   = d_in[i];
        else if (in_sizes[i] == 2 * EE)        eiv = d_in[i];
        else if (in_sizes[i] == HF * INF)      W   = d_in[i];
        else if (in_sizes[i] == 2 * OUTF)      a   = d_in[i];
    }
    const int* ei = (const int*)eiv;
    float* out = (float*)d_out;    // output dtype: float32 (verified)

    // Workspace (~20.2 MiB): flags | wbf | h | alpha_s | alpha_d | aw
    //                        | last_e64 | cnt | ovf_cnt | ovf_list | slots(u64)
    const size_t HN = (size_t)BB * NN * HF;
    char* p = (char*)d_ws;
    int*   flags    = (int*)p;                        p += 64;
    ushort* wbf     = (ushort*)p;                     p += 32768 * 2;
    ushort* h       = (ushort*)p;                     p += HN * 2;
    float* alpha_s  = (float*)p;                      p += (size_t)BB * NN * NH * 4;
    float* alpha_d  = (float*)p;                      p += (size_t)BB * NN * NH * 4;
    float* aw       = (float*)p;                      p += (size_t)BB * NN * NH * 4;
    u64*   last_e64 = (u64*)p;                        p += (size_t)NN * 8;
    int*   cnt      = (int*)p;                        p += (size_t)NN * 4;
    int*   ovf_cnt  = (int*)p;                        p += 64;
    int*   ovf_list = (int*)p;                        p += (size_t)OVF_CAP * 4;
    u64*   slots    = (u64*)p;

    k_init <<<(NN + 255) / 256, 256, 0, stream>>>((const ushort*)x, ei, W, flags, wbf,
                                                  cnt, last_e64, ovf_cnt);
    k_edge <<<EDGE_BLOCKS, 256, 0, stream>>>(ei, flags, cnt, slots, last_e64,
                                             ovf_cnt, ovf_list);
    k_gemm <<<GEMM_BLOCKS, 256, 0, stream>>>(x, wbf, a, flags, h, alpha_s, alpha_d);
    k_agg  <<<2048, 256, 0, stream>>>(slots, cnt, last_e64, alpha_s, alpha_d,
                                      h, aw, out);
    k_fix  <<<32, 256, 0, stream>>>(ei, flags, ovf_cnt, ovf_list, h, aw, out);
}

// Round 7
// 144.914 us; speedup vs baseline: 2.2240x; 1.0088x over previous
//
#include <hip/hip_runtime.h>
#include <hip/hip_bf16.h>

#define BB 2
#define NN 20000
#define EE 200000
#define INF 256
#define OUTF 32
#define NH 4
#define HF 128          // NH*OUTF
#define HF2 256         // 2*HF: node-major interleaved h row stride (ushorts)
#define NEG_SLOPE 0.2f
#define GEMM_BLOCKS 625  // 40000 rows / 64
#define EDGE_BLOCKS 782  // ceil(200000/256), 1 edge per thread
#define CAP 48           // u64 slots per node (deg ~ Poisson(10); overflow -> list)
#define OVF_CAP 8192

using bf16 = __hip_bfloat16;
typedef __attribute__((ext_vector_type(8))) short bf16x8;
typedef __attribute__((ext_vector_type(4))) float f32x4;
typedef unsigned long long u64;

__device__ __forceinline__ float bf2f(unsigned short s){ return __uint_as_float((unsigned)s << 16); }
__device__ __forceinline__ ushort f2bf_bits(float f){
    __hip_bfloat16 b = __float2bfloat16(f);
    return *(ushort*)&b;
}

__device__ __forceinline__ int get_src(const int* ei, int e, int f64){
    return f64 ? ei[2 * e] : ei[e];
}
__device__ __forceinline__ int get_dst(const int* ei, int e, int f64){
    return f64 ? ei[2 * EE + 2 * e] : ei[EE + e];
}

// h layout: [node][b][f*4+hd] -> row stride HF2=256 ushorts (512B). Per edge,
// the agg wave (b=0: lanes 0-31, b=1: lanes 32-63) reads ONE contiguous 512B.
__device__ __forceinline__ size_t hrow_of(int row){   // row = b*NN + n
    return (row >= NN) ? ((size_t)(row - NN) * 2 + 1) : ((size_t)row * 2);
}

// K0: init cnt/last_e64/ovf; blocks 0..15: dtype-detect (each block re-derives
// the flag deterministically) + W -> bf16 B-frag-linear wbf.
__global__ void k_init(const ushort* __restrict__ xr, const int* __restrict__ er,
                       const void* __restrict__ Wv,
                       int* __restrict__ flags, ushort* __restrict__ wbf,
                       int* __restrict__ cnt, u64* __restrict__ last_e64,
                       int* __restrict__ ovf_cnt){
    int i = blockIdx.x * blockDim.x + threadIdx.x;
    if (i < NN){ cnt[i] = 0; last_e64[i] = 0ULL; }
    if (i == 0) *ovf_cnt = 0;
    if (blockIdx.x < 16){
        __shared__ int cnt_big, cnt_nz;
        if (threadIdx.x == 0){ cnt_big = 0; cnt_nz = 0; }
        __syncthreads();
        int big = 0;
        for (int k = threadIdx.x; k < 8192; k += blockDim.x){
            unsigned e = ((unsigned)xr[2 * k] >> 7) & 0xff;   // bf16-exp of fp32 low half
            if (e >= 0xC0) big++;                              // impossible for N(0,1) bf16
        }
        int nz = 0;
        for (int k = threadIdx.x; k < 4096; k += blockDim.x){
            if (er[2 * k + 1] != 0) nz++;                      // int64 high words all zero
        }
        atomicAdd(&cnt_big, big);
        atomicAdd(&cnt_nz, nz);
        __syncthreads();
        if (blockIdx.x == 0 && threadIdx.x == 0){
            flags[0] = (cnt_big >= 16) ? 1 : 0;
            flags[1] = (cnt_nz == 0) ? 1 : 0;
        }
        const bool f32w = (cnt_big >= 16);
        int fr = blockIdx.x * 256 + threadIdx.x;               // 0..4095
        {
            int lane = fr & 63;
            int t    = (fr >> 6) & 3;
            int kc   = (fr >> 8) & 7;
            int ch   = fr >> 11;
            int col  = ch * 64 + t * 16 + (lane & 15);
            int kb   = kc * 32 + (lane >> 4) * 8;
            bf16x8 v;
            if (f32w){
                const float* wg = (const float*)Wv + (size_t)col * INF + kb;
                #pragma unroll
                for (int j = 0; j < 8; ++j) v[j] = (short)f2bf_bits(wg[j]);
            } else {
                const ushort* wg = (const ushort*)Wv + (size_t)col * INF + kb;
                #pragma unroll
                for (int j = 0; j < 8; ++j) v[j] = (short)wg[j];
            }
            *(bf16x8*)(wbf + (size_t)fr * 8) = v;
        }
    }
}

// K1: MERGED edge-build + MFMA GEMM (one dispatch, heterogeneous blocks).
// Edge blocks FIRST (atomic/latency-bound); GEMM blocks (MFMA/load-bound)
// overlap them on the complementary pipes. Data layouts = round-6 verified:
// packed u64 slot ((e+1)<<16)|dst, node-major interleaved h.
__global__ __launch_bounds__(256, 2)
void k_gemm(const void* __restrict__ xv_, const ushort* __restrict__ wbf,
            const void* __restrict__ av, const int* __restrict__ ei,
            const int* __restrict__ flags, ushort* __restrict__ h,
            float* __restrict__ alpha_s, float* __restrict__ alpha_d,
            int* __restrict__ cnt, u64* __restrict__ slots,
            u64* __restrict__ last_e64, int* __restrict__ ovf_cnt,
            int* __restrict__ ovf_list){
    if (blockIdx.x < EDGE_BLOCKS){
        int f64 = flags[1];
        int e = blockIdx.x * 256 + threadIdx.x;
        if (e < EE){
            int s = get_src(ei, e, f64);
            int d = get_dst(ei, e, f64);
            u64 pk = ((u64)(unsigned)(e + 1) << 16) | (unsigned)(d & 0xFFFF);
            int idx = atomicAdd(&cnt[s], 1);
            if (idx < CAP) slots[(size_t)s * CAP + idx] = pk;
            else {
                atomicMax(&last_e64[s], pk);    // rare: keeps le correct past CAP
                int o = atomicAdd(ovf_cnt, 1);
                if (o < OVF_CAP) ovf_list[o] = e;
            }
        }
        return;
    }

    const int bid  = blockIdx.x - EDGE_BLOCKS;
    const int tid  = threadIdx.x;
    const int lane = tid & 63;
    const int w    = tid >> 6;            // wave 0..3
    const int l15  = lane & 15;
    const int q    = lane >> 4;           // quad 0..3
    const bool f32 = flags[0] != 0;

    const int row0 = bid * 64 + w * 16;   // wave's 16 rows

    f32x4 acc[2][4];
    #pragma unroll
    for (int c = 0; c < 2; ++c)
        #pragma unroll
        for (int t = 0; t < 4; ++t) acc[c][t] = (f32x4){0.f, 0.f, 0.f, 0.f};

    if (f32){
        const float* xp = (const float*)xv_ + (size_t)(row0 + l15) * INF + q * 8;
        // 1-deep pipeline: cur pair in regs, next pair in flight.
        float4 c0 = ((const float4*)xp)[0];
        float4 c1 = ((const float4*)xp)[1];
        #pragma unroll
        for (int kc = 0; kc < 8; ++kc){
            float4 n0, n1;
            if (kc < 7){
                const float4* p = (const float4*)(xp + (kc + 1) * 32);
                n0 = p[0];
                n1 = p[1];
            }
            bf16x8 afrag;
            afrag[0] = (short)f2bf_bits(c0.x); afrag[1] = (short)f2bf_bits(c0.y);
            afrag[2] = (short)f2bf_bits(c0.z); afrag[3] = (short)f2bf_bits(c0.w);
            afrag[4] = (short)f2bf_bits(c1.x); afrag[5] = (short)f2bf_bits(c1.y);
            afrag[6] = (short)f2bf_bits(c1.z); afrag[7] = (short)f2bf_bits(c1.w);
            #pragma unroll
            for (int c = 0; c < 2; ++c){
                const ushort* wb = wbf + (size_t)c * 16384;
                #pragma unroll
                for (int t = 0; t < 4; ++t){
                    bf16x8 bfrag = *(const bf16x8*)(wb + (((size_t)kc * 4 + t) * 64 + lane) * 8);
                    acc[c][t] = __builtin_amdgcn_mfma_f32_16x16x32_bf16(afrag, bfrag, acc[c][t], 0, 0, 0);
                }
            }
            if (kc < 7){ c0 = n0; c1 = n1; }
        }
    } else {
        const ushort* xp = (const ushort*)xv_ + (size_t)(row0 + l15) * INF + q * 8;
        bf16x8 af = *(const bf16x8*)xp;
        #pragma unroll
        for (int kc = 0; kc < 8; ++kc){
            bf16x8 nf;
            if (kc < 7) nf = *(const bf16x8*)(xp + (kc + 1) * 32);
            #pragma unroll
            for (int c = 0; c < 2; ++c){
                const ushort* wb = wbf + (size_t)c * 16384;
                #pragma unroll
                for (int t = 0; t < 4; ++t){
                    bf16x8 bfrag = *(const bf16x8*)(wb + (((size_t)kc * 4 + t) * 64 + lane) * 8);
                    acc[c][t] = __builtin_amdgcn_mfma_f32_16x16x32_bf16(af, bfrag, acc[c][t], 0, 0, 0);
                }
            }
            if (kc < 7) af = nf;
        }
    }

    // ---- epilogue 1: h -> bf16, node-major interleaved [n][b][f*4+hd] ----
    #pragma unroll
    for (int r = 0; r < 4; ++r){
        int row = row0 + q * 4 + r;
        ushort* hp_ = h + hrow_of(row) * HF;
        #pragma unroll
        for (int t = 0; t < 2; ++t){    // t = f-half; f = t*16 + l15
            unsigned v0 = (unsigned)f2bf_bits(acc[0][t][r])
                        | ((unsigned)f2bf_bits(acc[0][t + 2][r]) << 16);  // heads 0,1
            unsigned v1 = (unsigned)f2bf_bits(acc[1][t][r])
                        | ((unsigned)f2bf_bits(acc[1][t + 2][r]) << 16);  // heads 2,3
            int f = t * 16 + l15;
            uint2 vv; vv.x = v0; vv.y = v1;
            *(uint2*)(hp_ + f * 4) = vv;
        }
    }

    // ---- epilogue 2: alpha dots from C registers ----
    float as_lo, as_hi, ad_lo, ad_hi;
    if (f32){
        const float* af = (const float*)av;
        as_lo = af[l15];        as_hi = af[16 + l15];
        ad_lo = af[OUTF + l15]; ad_hi = af[OUTF + 16 + l15];
    } else {
        const ushort* ab = (const ushort*)av;
        as_lo = bf2f(ab[l15]);        as_hi = bf2f(ab[16 + l15]);
        ad_lo = bf2f(ab[OUTF + l15]); ad_hi = bf2f(ab[OUTF + 16 + l15]);
    }
    #pragma unroll
    for (int r = 0; r < 4; ++r){
        int row = row0 + q * 4 + r;
        #pragma unroll
        for (int c = 0; c < 2; ++c){
            #pragma unroll
            for (int hp = 0; hp < 2; ++hp){
                int t0 = hp * 2, t1 = hp * 2 + 1;
                float ps = acc[c][t0][r] * as_lo + acc[c][t1][r] * as_hi;
                float pd = acc[c][t0][r] * ad_lo + acc[c][t1][r] * ad_hi;
                ps += __shfl_down(ps, 8, 16); pd += __shfl_down(pd, 8, 16);
                ps += __shfl_down(ps, 4, 16); pd += __shfl_down(pd, 4, 16);
                ps += __shfl_down(ps, 2, 16); pd += __shfl_down(pd, 2, 16);
                ps += __shfl_down(ps, 1, 16); pd += __shfl_down(pd, 1, 16);
                if (l15 == 0){
                    size_t o = (size_t)row * NH + c * 2 + hp;
                    alpha_s[o] = ps;
                    alpha_d[o] = pd;
                }
            }
        }
    }
}

// K3 (fused aw+agg): one wave per node. Bucket walk reads packed u64 slots:
// dst = pk & 0xFFFF (no ei gather), le = running max (dst of last edge free).
// Per edge: ONE contiguous 512B wave read from interleaved h.
__global__ __launch_bounds__(256)
void k_agg(const u64* __restrict__ slots, const int* __restrict__ cnt,
           const u64* __restrict__ last_e64,
           const float* __restrict__ alpha_s, const float* __restrict__ alpha_d,
           const ushort* __restrict__ h, float* __restrict__ aw,
           float* __restrict__ out_f){
    int lane = threadIdx.x & 63;
    int wid  = (blockIdx.x * blockDim.x + threadIdx.x) >> 6;
    int nw   = (gridDim.x * blockDim.x) >> 6;
    int b = lane >> 5;
    int f = lane & 31;
    int c  = lane & 7;          // softmax work item: bb = c>>2, hh = c&3
    int bb = c >> 2;
    int hh = c & 3;
    const ushort* hb = h + b * HF + f * 4;   // + d*HF2 per gather
    for (int n = wid; n < NN; n += nw){
        int m = cnt[n]; if (m > CAP) m = CAP;
        u64 le = last_e64[n];                 // 0 unless overflow happened

        const u64* sl = slots + (size_t)n * CAP;
        float ax = 0.f, ay = 0.f, az = 0.f, aww = 0.f;
        int i = 0;
        for (; i + 4 <= m; i += 4){
            ulonglong2 p0 = *(const ulonglong2*)(sl + i);       // uniform 16B
            ulonglong2 p1 = *(const ulonglong2*)(sl + i + 2);
            le = p0.x > le ? p0.x : le;  le = p0.y > le ? p0.y : le;
            le = p1.x > le ? p1.x : le;  le = p1.y > le ? p1.y : le;
            int d0 = (int)(p0.x & 0xFFFFULL);
            int d1 = (int)(p0.y & 0xFFFFULL);
            int d2 = (int)(p1.x & 0xFFFFULL);
            int d3 = (int)(p1.y & 0xFFFFULL);
            ushort4 u0 = *(const ushort4*)(hb + (size_t)d0 * HF2);
            ushort4 u1 = *(const ushort4*)(hb + (size_t)d1 * HF2);
            ushort4 u2 = *(const ushort4*)(hb + (size_t)d2 * HF2);
            ushort4 u3 = *(const ushort4*)(hb + (size_t)d3 * HF2);
            ax += bf2f(u0.x) + bf2f(u1.x) + bf2f(u2.x) + bf2f(u3.x);
            ay += bf2f(u0.y) + bf2f(u1.y) + bf2f(u2.y) + bf2f(u3.y);
            az += bf2f(u0.z) + bf2f(u1.z) + bf2f(u2.z) + bf2f(u3.z);
            aww += bf2f(u0.w) + bf2f(u1.w) + bf2f(u2.w) + bf2f(u3.w);
        }
        for (; i < m; ++i){
            u64 pk = sl[i];
            le = pk > le ? pk : le;
            int d = (int)(pk & 0xFFFFULL);
            ushort4 u = *(const ushort4*)(hb + (size_t)d * HF2);
            ax += bf2f(u.x); ay += bf2f(u.y); az += bf2f(u.z); aww += bf2f(u.w);
        }

        // per-(bb,hh) attention weight (replicated x8 across the wave)
        float my_aw = 0.f;
        if (le != 0ULL){
            int d = (int)(le & 0xFFFFULL);      // dst of last edge: free
            float ss = alpha_s[((size_t)bb * NN + n) * NH + hh]
                     + alpha_d[((size_t)bb * NN + d) * NH + hh];
            float so = alpha_s[((size_t)(1 - bb) * NN + n) * NH + hh]
                     + alpha_d[((size_t)(1 - bb) * NN + d) * NH + hh];
            ss = ss > 0.f ? ss : NEG_SLOPE * ss;
            so = so > 0.f ? so : NEG_SLOPE * so;
            float mx = fmaxf(ss, so);
            float e0 = __expf(ss - mx);
            float e1 = __expf(so - mx);
            my_aw = 0.25f * e0 / (e0 + e1);
        }
        if (lane < 8) aw[((size_t)bb * NN + n) * NH + hh] = my_aw;  // for k_fix

        float aw0 = __shfl(my_aw, (b << 2) + 0, 8);
        float aw1 = __shfl(my_aw, (b << 2) + 1, 8);
        float aw2 = __shfl(my_aw, (b << 2) + 2, 8);
        float aw3 = __shfl(my_aw, (b << 2) + 3, 8);

        out_f[((size_t)b * NN + n) * OUTF + f] =
            aw0 * ax + aw1 * ay + aw2 * az + aw3 * aww;
    }
}

// K4: overflow fix-up (normally empty). One wave per overflow edge, atomics.
__global__ void k_fix(const int* __restrict__ ei, const int* __restrict__ flags,
                      const int* __restrict__ ovf_cnt, const int* __restrict__ ovf_list,
                      const ushort* __restrict__ h, const float* __restrict__ aw,
                      float* __restrict__ out_f){
    int lane = threadIdx.x & 63;
    int wid  = (blockIdx.x * blockDim.x + threadIdx.x) >> 6;
    int nw   = (gridDim.x * blockDim.x) >> 6;
    int b = lane >> 5;
    int f = lane & 31;
    int M = *ovf_cnt; if (M > OVF_CAP) M = OVF_CAP;
    int f64 = flags[1];
    for (int i = wid; i < M; i += nw){
        int e = ovf_list[i];
        int s = get_src(ei, e, f64);
        int d = get_dst(ei, e, f64);
        float4 awv = *(const float4*)(aw + ((size_t)b * NN + s) * NH);
        ushort4 u = *(const ushort4*)(h + ((size_t)d * 2 + b) * HF + f * 4);
        float acc = awv.x * bf2f(u.x) + awv.y * bf2f(u.y)
                  + awv.z * bf2f(u.z) + awv.w * bf2f(u.w);
        atomicAdd(&out_f[((size_t)b * NN + s) * OUTF + f], acc);
    }
}

extern "C" void kernel_launch(void* const* d_in, const int* in_sizes, int n_in,
                              void* d_out, int out_size, void* d_ws, size_t ws_size,
                              hipStream_t stream){
    const void* x = d_in[0]; const void* eiv = d_in[1];
    const void* W = d_in[2]; const void* a  = d_in[3];
    for (int i = 0; i < n_in; ++i){
        if      (in_sizes[i] == BB * NN * INF) x   = d_in[i];
        else if (in_sizes[i] == 2 * EE)        eiv = d_in[i];
        else if (in_sizes[i] == HF * INF)      W   = d_in[i];
        else if (in_sizes[i] == 2 * OUTF)      a   = d_in[i];
    }
    const int* ei = (const int*)eiv;
    float* out = (float*)d_out;    // output dtype: float32 (verified)

    // Workspace (~20.2 MiB): flags | wbf | h | alpha_s | alpha_d | aw
    //                        | last_e64 | cnt | ovf_cnt | ovf_list | slots(u64)
    const size_t HN = (size_t)BB * NN * HF;
    char* p = (char*)d_ws;
    int*   flags    = (int*)p;                        p += 64;
    ushort* wbf     = (ushort*)p;                     p += 32768 * 2;
    ushort* h       = (ushort*)p;                     p += HN * 2;
    float* alpha_s  = (float*)p;                      p += (size_t)BB * NN * NH * 4;
    float* alpha_d  = (float*)p;                      p += (size_t)BB * NN * NH * 4;
    float* aw       = (float*)p;                      p += (size_t)BB * NN * NH * 4;
    u64*   last_e64 = (u64*)p;                        p += (size_t)NN * 8;
    int*   cnt      = (int*)p;                        p += (size_t)NN * 4;
    int*   ovf_cnt  = (int*)p;                        p += 64;
    int*   ovf_list = (int*)p;                        p += (size_t)OVF_CAP * 4;
    u64*   slots    = (u64*)p;

    k_init <<<(NN + 255) / 256, 256, 0, stream>>>((const ushort*)x, ei, W, flags, wbf,
                                                  cnt, last_e64, ovf_cnt);
    k_gemm <<<EDGE_BLOCKS + GEMM_BLOCKS, 256, 0, stream>>>(x, wbf, a, ei, flags, h,
                                                           alpha_s, alpha_d, cnt,
                                                           slots, last_e64, ovf_cnt,
                                                           ovf_list);
    k_agg  <<<2048, 256, 0, stream>>>(slots, cnt, last_e64, alpha_s, alpha_d,
                                      h, aw, out);
    k_fix  <<<32, 256, 0, stream>>>(ei, flags, ovf_cnt, ovf_list, h, aw, out);
}

// Round 8
// 143.042 us; speedup vs baseline: 2.2531x; 1.0131x over previous
//
#include <hip/hip_runtime.h>
#include <hip/hip_bf16.h>

#define BB 2
#define NN 20000
#define EE 200000
#define INF 256
#define OUTF 32
#define NH 4
#define HF 128          // NH*OUTF
#define HF2 256         // 2*HF: node-major interleaved h row stride (ushorts)
#define NEG_SLOPE 0.2f
#define GEMM_BLOCKS 1250 // 40000 rows / 32; wave = 16 rows x 1 col-half
#define EDGE_BLOCKS 782  // ceil(200000/256), 1 edge per thread
#define CAP 48           // u64 slots per node (deg ~ Poisson(10); overflow -> list)
#define OVF_CAP 8192

using bf16 = __hip_bfloat16;
typedef __attribute__((ext_vector_type(8))) short bf16x8;
typedef __attribute__((ext_vector_type(4))) float f32x4;
typedef unsigned long long u64;

__device__ __forceinline__ float bf2f(unsigned short s){ return __uint_as_float((unsigned)s << 16); }
__device__ __forceinline__ ushort f2bf_bits(float f){
    __hip_bfloat16 b = __float2bfloat16(f);
    return *(ushort*)&b;
}

__device__ __forceinline__ int get_src(const int* ei, int e, int f64){
    return f64 ? ei[2 * e] : ei[e];
}
__device__ __forceinline__ int get_dst(const int* ei, int e, int f64){
    return f64 ? ei[2 * EE + 2 * e] : ei[EE + e];
}

// h layout: [node][b][f*4+hd] -> row stride HF2=256 ushorts (512B). Per edge,
// the agg wave (b=0: lanes 0-31, b=1: lanes 32-63) reads ONE contiguous 512B.
__device__ __forceinline__ size_t hrow_of(int row){   // row = b*NN + n
    return (row >= NN) ? ((size_t)(row - NN) * 2 + 1) : ((size_t)row * 2);
}

// K0: init cnt/last_e64/ovf; blocks 0..15: dtype-detect (each block re-derives
// the flag deterministically) + W -> bf16 B-frag-linear wbf.
__global__ void k_init(const ushort* __restrict__ xr, const int* __restrict__ er,
                       const void* __restrict__ Wv,
                       int* __restrict__ flags, ushort* __restrict__ wbf,
                       int* __restrict__ cnt, u64* __restrict__ last_e64,
                       int* __restrict__ ovf_cnt){
    int i = blockIdx.x * blockDim.x + threadIdx.x;
    if (i < NN){ cnt[i] = 0; last_e64[i] = 0ULL; }
    if (i == 0) *ovf_cnt = 0;
    if (blockIdx.x < 16){
        __shared__ int cnt_big, cnt_nz;
        if (threadIdx.x == 0){ cnt_big = 0; cnt_nz = 0; }
        __syncthreads();
        int big = 0;
        for (int k = threadIdx.x; k < 8192; k += blockDim.x){
            unsigned e = ((unsigned)xr[2 * k] >> 7) & 0xff;   // bf16-exp of fp32 low half
            if (e >= 0xC0) big++;                              // impossible for N(0,1) bf16
        }
        int nz = 0;
        for (int k = threadIdx.x; k < 4096; k += blockDim.x){
            if (er[2 * k + 1] != 0) nz++;                      // int64 high words all zero
        }
        atomicAdd(&cnt_big, big);
        atomicAdd(&cnt_nz, nz);
        __syncthreads();
        if (blockIdx.x == 0 && threadIdx.x == 0){
            flags[0] = (cnt_big >= 16) ? 1 : 0;
            flags[1] = (cnt_nz == 0) ? 1 : 0;
        }
        const bool f32w = (cnt_big >= 16);
        int fr = blockIdx.x * 256 + threadIdx.x;               // 0..4095
        {
            int lane = fr & 63;
            int t    = (fr >> 6) & 3;
            int kc   = (fr >> 8) & 7;
            int ch   = fr >> 11;
            int col  = ch * 64 + t * 16 + (lane & 15);
            int kb   = kc * 32 + (lane >> 4) * 8;
            bf16x8 v;
            if (f32w){
                const float* wg = (const float*)Wv + (size_t)col * INF + kb;
                #pragma unroll
                for (int j = 0; j < 8; ++j) v[j] = (short)f2bf_bits(wg[j]);
            } else {
                const ushort* wg = (const ushort*)Wv + (size_t)col * INF + kb;
                #pragma unroll
                for (int j = 0; j < 8; ++j) v[j] = (short)wg[j];
            }
            *(bf16x8*)(wbf + (size_t)fr * 8) = v;
        }
    }
}

// K1: MERGED edge-build + MFMA GEMM (heterogeneous blocks; edge blocks first).
// GEMM: 1250 blocks x 32 rows; wave = 16 rows x ONE col-half (2x TLP vs r7).
// All 16 x-loads issued as NAMED regs + sched_barrier(0) pin -> 256B/wave in
// flight (compiler cannot sink the loads; no array -> no scratch).
__global__ __launch_bounds__(256, 2)
void k_gemm(const void* __restrict__ xv_, const ushort* __restrict__ wbf,
            const void* __restrict__ av, const int* __restrict__ ei,
            const int* __restrict__ flags, ushort* __restrict__ h,
            float* __restrict__ alpha_s, float* __restrict__ alpha_d,
            int* __restrict__ cnt, u64* __restrict__ slots,
            u64* __restrict__ last_e64, int* __restrict__ ovf_cnt,
            int* __restrict__ ovf_list){
    if (blockIdx.x < EDGE_BLOCKS){
        int f64 = flags[1];
        int e = blockIdx.x * 256 + threadIdx.x;
        if (e < EE){
            int s = get_src(ei, e, f64);
            int d = get_dst(ei, e, f64);
            u64 pk = ((u64)(unsigned)(e + 1) << 16) | (unsigned)(d & 0xFFFF);
            int idx = atomicAdd(&cnt[s], 1);
            if (idx < CAP) slots[(size_t)s * CAP + idx] = pk;
            else {
                atomicMax(&last_e64[s], pk);    // rare: keeps le correct past CAP
                int o = atomicAdd(ovf_cnt, 1);
                if (o < OVF_CAP) ovf_list[o] = e;
            }
        }
        return;
    }

    const int bid  = blockIdx.x - EDGE_BLOCKS;
    const int tid  = threadIdx.x;
    const int lane = tid & 63;
    const int w    = tid >> 6;            // wave 0..3
    const int l15  = lane & 15;
    const int q    = lane >> 4;           // quad 0..3
    const bool f32 = flags[0] != 0;

    const int row0 = bid * 32 + (w >> 1) * 16;  // wave's 16 rows
    const int ch   = w & 1;                     // this wave's col-half
    const int hd0  = ch * 2;                    // heads 0,1 or 2,3
    const ushort* wb = wbf + (size_t)ch * 16384;

    f32x4 acc[4];
    #pragma unroll
    for (int t = 0; t < 4; ++t) acc[t] = (f32x4){0.f, 0.f, 0.f, 0.f};

    if (f32){
        const float* xp = (const float*)xv_ + (size_t)(row0 + l15) * INF + q * 8;
        // 16 NAMED float4 loads, all issued before the MFMA loop (pinned).
        float4 a0 = ((const float4*)(xp +   0))[0], b0 = ((const float4*)(xp +   0))[1];
        float4 a1 = ((const float4*)(xp +  32))[0], b1 = ((const float4*)(xp +  32))[1];
        float4 a2 = ((const float4*)(xp +  64))[0], b2 = ((const float4*)(xp +  64))[1];
        float4 a3 = ((const float4*)(xp +  96))[0], b3 = ((const float4*)(xp +  96))[1];
        float4 a4 = ((const float4*)(xp + 128))[0], b4 = ((const float4*)(xp + 128))[1];
        float4 a5 = ((const float4*)(xp + 160))[0], b5 = ((const float4*)(xp + 160))[1];
        float4 a6 = ((const float4*)(xp + 192))[0], b6 = ((const float4*)(xp + 192))[1];
        float4 a7 = ((const float4*)(xp + 224))[0], b7 = ((const float4*)(xp + 224))[1];
        __builtin_amdgcn_sched_barrier(0);   // do NOT sink these loads

        #define KSTEP(KC, LO, HI)                                                        \
        {                                                                                \
            bf16x8 afrag;                                                                \
            afrag[0] = (short)f2bf_bits(LO.x); afrag[1] = (short)f2bf_bits(LO.y);        \
            afrag[2] = (short)f2bf_bits(LO.z); afrag[3] = (short)f2bf_bits(LO.w);        \
            afrag[4] = (short)f2bf_bits(HI.x); afrag[5] = (short)f2bf_bits(HI.y);        \
            afrag[6] = (short)f2bf_bits(HI.z); afrag[7] = (short)f2bf_bits(HI.w);        \
            _Pragma("unroll")                                                            \
            for (int t = 0; t < 4; ++t){                                                 \
                bf16x8 bfrag = *(const bf16x8*)(wb + (((size_t)(KC) * 4 + t) * 64 + lane) * 8); \
                acc[t] = __builtin_amdgcn_mfma_f32_16x16x32_bf16(afrag, bfrag, acc[t], 0, 0, 0); \
            }                                                                            \
        }
        KSTEP(0, a0, b0) KSTEP(1, a1, b1) KSTEP(2, a2, b2) KSTEP(3, a3, b3)
        KSTEP(4, a4, b4) KSTEP(5, a5, b5) KSTEP(6, a6, b6) KSTEP(7, a7, b7)
        #undef KSTEP
    } else {
        const ushort* xp = (const ushort*)xv_ + (size_t)(row0 + l15) * INF + q * 8;
        bf16x8 f0 = *(const bf16x8*)(xp +   0);
        bf16x8 f1 = *(const bf16x8*)(xp +  32);
        bf16x8 f2 = *(const bf16x8*)(xp +  64);
        bf16x8 f3 = *(const bf16x8*)(xp +  96);
        bf16x8 f4 = *(const bf16x8*)(xp + 128);
        bf16x8 f5 = *(const bf16x8*)(xp + 160);
        bf16x8 f6 = *(const bf16x8*)(xp + 192);
        bf16x8 f7 = *(const bf16x8*)(xp + 224);
        __builtin_amdgcn_sched_barrier(0);

        #define KSTEP(KC, AF)                                                            \
        {                                                                                \
            _Pragma("unroll")                                                            \
            for (int t = 0; t < 4; ++t){                                                 \
                bf16x8 bfrag = *(const bf16x8*)(wb + (((size_t)(KC) * 4 + t) * 64 + lane) * 8); \
                acc[t] = __builtin_amdgcn_mfma_f32_16x16x32_bf16(AF, bfrag, acc[t], 0, 0, 0); \
            }                                                                            \
        }
        KSTEP(0, f0) KSTEP(1, f1) KSTEP(2, f2) KSTEP(3, f3)
        KSTEP(4, f4) KSTEP(5, f5) KSTEP(6, f6) KSTEP(7, f7)
        #undef KSTEP
    }

    // ---- epilogue 1: h -> bf16, node-major interleaved [n][b][f*4+hd] ----
    #pragma unroll
    for (int r = 0; r < 4; ++r){
        int row = row0 + q * 4 + r;
        ushort* hp_ = h + hrow_of(row) * HF + hd0;
        #pragma unroll
        for (int t = 0; t < 2; ++t){    // t = f-half; f = t*16 + l15
            unsigned v = (unsigned)f2bf_bits(acc[t][r])
                       | ((unsigned)f2bf_bits(acc[t + 2][r]) << 16);  // this half's 2 heads
            int f = t * 16 + l15;
            *(unsigned*)(hp_ + f * 4) = v;
        }
    }

    // ---- epilogue 2: alpha dots from C registers (this col-half's 2 heads) ----
    float as_lo, as_hi, ad_lo, ad_hi;
    if (f32){
        const float* af = (const float*)av;
        as_lo = af[l15];        as_hi = af[16 + l15];
        ad_lo = af[OUTF + l15]; ad_hi = af[OUTF + 16 + l15];
    } else {
        const ushort* ab = (const ushort*)av;
        as_lo = bf2f(ab[l15]);        as_hi = bf2f(ab[16 + l15]);
        ad_lo = bf2f(ab[OUTF + l15]); ad_hi = bf2f(ab[OUTF + 16 + l15]);
    }
    #pragma unroll
    for (int r = 0; r < 4; ++r){
        int row = row0 + q * 4 + r;
        #pragma unroll
        for (int hp = 0; hp < 2; ++hp){
            int t0 = hp * 2, t1 = hp * 2 + 1;
            float ps = acc[t0][r] * as_lo + acc[t1][r] * as_hi;
            float pd = acc[t0][r] * ad_lo + acc[t1][r] * ad_hi;
            ps += __shfl_down(ps, 8, 16); pd += __shfl_down(pd, 8, 16);
            ps += __shfl_down(ps, 4, 16); pd += __shfl_down(pd, 4, 16);
            ps += __shfl_down(ps, 2, 16); pd += __shfl_down(pd, 2, 16);
            ps += __shfl_down(ps, 1, 16); pd += __shfl_down(pd, 1, 16);
            if (l15 == 0){
                size_t o = (size_t)row * NH + hd0 + hp;
                alpha_s[o] = ps;
                alpha_d[o] = pd;
            }
        }
    }
}

// K3 (fused aw+agg): one wave per node. Bucket walk reads packed u64 slots:
// dst = pk & 0xFFFF (no ei gather), le = running max (dst of last edge free).
// Per edge: ONE contiguous 512B wave read from interleaved h.
__global__ __launch_bounds__(256)
void k_agg(const u64* __restrict__ slots, const int* __restrict__ cnt,
           const u64* __restrict__ last_e64,
           const float* __restrict__ alpha_s, const float* __restrict__ alpha_d,
           const ushort* __restrict__ h, float* __restrict__ aw,
           float* __restrict__ out_f){
    int lane = threadIdx.x & 63;
    int wid  = (blockIdx.x * blockDim.x + threadIdx.x) >> 6;
    int nw   = (gridDim.x * blockDim.x) >> 6;
    int b = lane >> 5;
    int f = lane & 31;
    int c  = lane & 7;          // softmax work item: bb = c>>2, hh = c&3
    int bb = c >> 2;
    int hh = c & 3;
    const ushort* hb = h + b * HF + f * 4;   // + d*HF2 per gather
    for (int n = wid; n < NN; n += nw){
        int m = cnt[n]; if (m > CAP) m = CAP;
        u64 le = last_e64[n];                 // 0 unless overflow happened

        const u64* sl = slots + (size_t)n * CAP;
        float ax = 0.f, ay = 0.f, az = 0.f, aww = 0.f;
        int i = 0;
        for (; i + 4 <= m; i += 4){
            ulonglong2 p0 = *(const ulonglong2*)(sl + i);       // uniform 16B
            ulonglong2 p1 = *(const ulonglong2*)(sl + i + 2);
            le = p0.x > le ? p0.x : le;  le = p0.y > le ? p0.y : le;
            le = p1.x > le ? p1.x : le;  le = p1.y > le ? p1.y : le;
            int d0 = (int)(p0.x & 0xFFFFULL);
            int d1 = (int)(p0.y & 0xFFFFULL);
            int d2 = (int)(p1.x & 0xFFFFULL);
            int d3 = (int)(p1.y & 0xFFFFULL);
            ushort4 u0 = *(const ushort4*)(hb + (size_t)d0 * HF2);
            ushort4 u1 = *(const ushort4*)(hb + (size_t)d1 * HF2);
            ushort4 u2 = *(const ushort4*)(hb + (size_t)d2 * HF2);
            ushort4 u3 = *(const ushort4*)(hb + (size_t)d3 * HF2);
            ax += bf2f(u0.x) + bf2f(u1.x) + bf2f(u2.x) + bf2f(u3.x);
            ay += bf2f(u0.y) + bf2f(u1.y) + bf2f(u2.y) + bf2f(u3.y);
            az += bf2f(u0.z) + bf2f(u1.z) + bf2f(u2.z) + bf2f(u3.z);
            aww += bf2f(u0.w) + bf2f(u1.w) + bf2f(u2.w) + bf2f(u3.w);
        }
        for (; i < m; ++i){
            u64 pk = sl[i];
            le = pk > le ? pk : le;
            int d = (int)(pk & 0xFFFFULL);
            ushort4 u = *(const ushort4*)(hb + (size_t)d * HF2);
            ax += bf2f(u.x); ay += bf2f(u.y); az += bf2f(u.z); aww += bf2f(u.w);
        }

        // per-(bb,hh) attention weight (replicated x8 across the wave)
        float my_aw = 0.f;
        if (le != 0ULL){
            int d = (int)(le & 0xFFFFULL);      // dst of last edge: free
            float ss = alpha_s[((size_t)bb * NN + n) * NH + hh]
                     + alpha_d[((size_t)bb * NN + d) * NH + hh];
            float so = alpha_s[((size_t)(1 - bb) * NN + n) * NH + hh]
                     + alpha_d[((size_t)(1 - bb) * NN + d) * NH + hh];
            ss = ss > 0.f ? ss : NEG_SLOPE * ss;
            so = so > 0.f ? so : NEG_SLOPE * so;
            float mx = fmaxf(ss, so);
            float e0 = __expf(ss - mx);
            float e1 = __expf(so - mx);
            my_aw = 0.25f * e0 / (e0 + e1);
        }
        if (lane < 8) aw[((size_t)bb * NN + n) * NH + hh] = my_aw;  // for k_fix

        float aw0 = __shfl(my_aw, (b << 2) + 0, 8);
        float aw1 = __shfl(my_aw, (b << 2) + 1, 8);
        float aw2 = __shfl(my_aw, (b << 2) + 2, 8);
        float aw3 = __shfl(my_aw, (b << 2) + 3, 8);

        out_f[((size_t)b * NN + n) * OUTF + f] =
            aw0 * ax + aw1 * ay + aw2 * az + aw3 * aww;
    }
}

// K4: overflow fix-up (normally empty). One wave per overflow edge, atomics.
__global__ void k_fix(const int* __restrict__ ei, const int* __restrict__ flags,
                      const int* __restrict__ ovf_cnt, const int* __restrict__ ovf_list,
                      const ushort* __restrict__ h, const float* __restrict__ aw,
                      float* __restrict__ out_f){
    int lane = threadIdx.x & 63;
    int wid  = (blockIdx.x * blockDim.x + threadIdx.x) >> 6;
    int nw   = (gridDim.x * blockDim.x) >> 6;
    int b = lane >> 5;
    int f = lane & 31;
    int M = *ovf_cnt; if (M > OVF_CAP) M = OVF_CAP;
    int f64 = flags[1];
    for (int i = wid; i < M; i += nw){
        int e = ovf_list[i];
        int s = get_src(ei, e, f64);
        int d = get_dst(ei, e, f64);
        float4 awv = *(const float4*)(aw + ((size_t)b * NN + s) * NH);
        ushort4 u = *(const ushort4*)(h + ((size_t)d * 2 + b) * HF + f * 4);
        float acc = awv.x * bf2f(u.x) + awv.y * bf2f(u.y)
                  + awv.z * bf2f(u.z) + awv.w * bf2f(u.w);
        atomicAdd(&out_f[((size_t)b * NN + s) * OUTF + f], acc);
    }
}

extern "C" void kernel_launch(void* const* d_in, const int* in_sizes, int n_in,
                              void* d_out, int out_size, void* d_ws, size_t ws_size,
                              hipStream_t stream){
    const void* x = d_in[0]; const void* eiv = d_in[1];
    const void* W = d_in[2]; const void* a  = d_in[3];
    for (int i = 0; i < n_in; ++i){
        if      (in_sizes[i] == BB * NN * INF) x   = d_in[i];
        else if (in_sizes[i] == 2 * EE)        eiv = d_in[i];
        else if (in_sizes[i] == HF * INF)      W   = d_in[i];
        else if (in_sizes[i] == 2 * OUTF)      a   = d_in[i];
    }
    const int* ei = (const int*)eiv;
    float* out = (float*)d_out;    // output dtype: float32 (verified)

    // Workspace (~20.2 MiB): flags | wbf | h | alpha_s | alpha_d | aw
    //                        | last_e64 | cnt | ovf_cnt | ovf_list | slots(u64)
    const size_t HN = (size_t)BB * NN * HF;
    char* p = (char*)d_ws;
    int*   flags    = (int*)p;                        p += 64;
    ushort* wbf     = (ushort*)p;                     p += 32768 * 2;
    ushort* h       = (ushort*)p;                     p += HN * 2;
    float* alpha_s  = (float*)p;                      p += (size_t)BB * NN * NH * 4;
    float* alpha_d  = (float*)p;                      p += (size_t)BB * NN * NH * 4;
    float* aw       = (float*)p;                      p += (size_t)BB * NN * NH * 4;
    u64*   last_e64 = (u64*)p;                        p += (size_t)NN * 8;
    int*   cnt      = (int*)p;                        p += (size_t)NN * 4;
    int*   ovf_cnt  = (int*)p;                        p += 64;
    int*   ovf_list = (int*)p;                        p += (size_t)OVF_CAP * 4;
    u64*   slots    = (u64*)p;

    k_init <<<(NN + 255) / 256, 256, 0, stream>>>((const ushort*)x, ei, W, flags, wbf,
                                                  cnt, last_e64, ovf_cnt);
    k_gemm <<<EDGE_BLOCKS + GEMM_BLOCKS, 256, 0, stream>>>(x, wbf, a, ei, flags, h,
                                                           alpha_s, alpha_d, cnt,
                                                           slots, last_e64, ovf_cnt,
                                                           ovf_list);
    k_agg  <<<2048, 256, 0, stream>>>(slots, cnt, last_e64, alpha_s, alpha_d,
                                      h, aw, out);
    k_fix  <<<32, 256, 0, stream>>>(ei, flags, ovf_cnt, ovf_list, h, aw, out);
}

// Round 9
// 140.715 us; speedup vs baseline: 2.2903x; 1.0165x over previous
//
#include <hip/hip_runtime.h>
#include <hip/hip_bf16.h>

#define BB 2
#define NN 20000
#define EE 200000
#define INF 256
#define OUTF 32
#define NH 4
#define HF 128          // NH*OUTF
#define HF2 256         // 2*HF: node-major interleaved h row stride (ushorts)
#define NEG_SLOPE 0.2f
#define GEMM_BLOCKS 1250 // 40000 rows / 32; wave = 16 rows x 1 col-half
#define EDGE_BLOCKS 782  // ceil(200000/256), 1 edge per thread
#define CAP 48           // u64 slots per node (deg ~ Poisson(10); overflow -> list)
#define OVF_CAP 8192

using bf16 = __hip_bfloat16;
typedef __attribute__((ext_vector_type(8))) short bf16x8;
typedef __attribute__((ext_vector_type(4))) float f32x4;
typedef unsigned long long u64;

__device__ __forceinline__ float bf2f(unsigned short s){ return __uint_as_float((unsigned)s << 16); }
__device__ __forceinline__ ushort f2bf_bits(float f){
    __hip_bfloat16 b = __float2bfloat16(f);
    return *(ushort*)&b;
}

__device__ __forceinline__ int get_src(const int* ei, int e, int f64){
    return f64 ? ei[2 * e] : ei[e];
}
__device__ __forceinline__ int get_dst(const int* ei, int e, int f64){
    return f64 ? ei[2 * EE + 2 * e] : ei[EE + e];
}

// h layout: [node][b][f*4+hd] -> row stride HF2=256 ushorts (512B). Per edge,
// the agg wave (b=0: lanes 0-31, b=1: lanes 32-63) reads ONE contiguous 512B.
__device__ __forceinline__ size_t hrow_of(int row){   // row = b*NN + n
    return (row >= NN) ? ((size_t)(row - NN) * 2 + 1) : ((size_t)row * 2);
}

// K0: init cnt/last_e64/ovf; blocks 0..15: dtype-detect (each block re-derives
// the flag deterministically) + W -> bf16 B-frag-linear wbf.
__global__ void k_init(const ushort* __restrict__ xr, const int* __restrict__ er,
                       const void* __restrict__ Wv,
                       int* __restrict__ flags, ushort* __restrict__ wbf,
                       int* __restrict__ cnt, u64* __restrict__ last_e64,
                       int* __restrict__ ovf_cnt){
    int i = blockIdx.x * blockDim.x + threadIdx.x;
    if (i < NN){ cnt[i] = 0; last_e64[i] = 0ULL; }
    if (i == 0) *ovf_cnt = 0;
    if (blockIdx.x < 16){
        __shared__ int cnt_big, cnt_nz;
        if (threadIdx.x == 0){ cnt_big = 0; cnt_nz = 0; }
        __syncthreads();
        int big = 0;
        for (int k = threadIdx.x; k < 8192; k += blockDim.x){
            unsigned e = ((unsigned)xr[2 * k] >> 7) & 0xff;   // bf16-exp of fp32 low half
            if (e >= 0xC0) big++;                              // impossible for N(0,1) bf16
        }
        int nz = 0;
        for (int k = threadIdx.x; k < 4096; k += blockDim.x){
            if (er[2 * k + 1] != 0) nz++;                      // int64 high words all zero
        }
        atomicAdd(&cnt_big, big);
        atomicAdd(&cnt_nz, nz);
        __syncthreads();
        if (blockIdx.x == 0 && threadIdx.x == 0){
            flags[0] = (cnt_big >= 16) ? 1 : 0;
            flags[1] = (cnt_nz == 0) ? 1 : 0;
        }
        const bool f32w = (cnt_big >= 16);
        int fr = blockIdx.x * 256 + threadIdx.x;               // 0..4095
        {
            int lane = fr & 63;
            int t    = (fr >> 6) & 3;
            int kc   = (fr >> 8) & 7;
            int ch   = fr >> 11;
            int col  = ch * 64 + t * 16 + (lane & 15);
            int kb   = kc * 32 + (lane >> 4) * 8;
            bf16x8 v;
            if (f32w){
                const float* wg = (const float*)Wv + (size_t)col * INF + kb;
                #pragma unroll
                for (int j = 0; j < 8; ++j) v[j] = (short)f2bf_bits(wg[j]);
            } else {
                const ushort* wg = (const ushort*)Wv + (size_t)col * INF + kb;
                #pragma unroll
                for (int j = 0; j < 8; ++j) v[j] = (short)wg[j];
            }
            *(bf16x8*)(wbf + (size_t)fr * 8) = v;
        }
    }
}

// K1: MERGED edge-build + MFMA GEMM (heterogeneous blocks; edge blocks first).
// GEMM: 1250 blocks x 32 rows; wave = 16 rows x ONE col-half.
// All 16 x-loads issued as NAMED regs + sched_barrier(0) pin.
__global__ __launch_bounds__(256, 2)
void k_gemm(const void* __restrict__ xv_, const ushort* __restrict__ wbf,
            const void* __restrict__ av, const int* __restrict__ ei,
            const int* __restrict__ flags, ushort* __restrict__ h,
            float* __restrict__ alpha_s, float* __restrict__ alpha_d,
            int* __restrict__ cnt, u64* __restrict__ slots,
            u64* __restrict__ last_e64, int* __restrict__ ovf_cnt,
            int* __restrict__ ovf_list){
    if (blockIdx.x < EDGE_BLOCKS){
        int f64 = flags[1];
        int e = blockIdx.x * 256 + threadIdx.x;
        if (e < EE){
            int s = get_src(ei, e, f64);
            int d = get_dst(ei, e, f64);
            u64 pk = ((u64)(unsigned)(e + 1) << 16) | (unsigned)(d & 0xFFFF);
            int idx = atomicAdd(&cnt[s], 1);
            if (idx < CAP) slots[(size_t)s * CAP + idx] = pk;
            else {
                atomicMax(&last_e64[s], pk);    // rare: keeps le correct past CAP
                int o = atomicAdd(ovf_cnt, 1);
                if (o < OVF_CAP) ovf_list[o] = e;
            }
        }
        return;
    }

    const int bid  = blockIdx.x - EDGE_BLOCKS;
    const int tid  = threadIdx.x;
    const int lane = tid & 63;
    const int w    = tid >> 6;            // wave 0..3
    const int l15  = lane & 15;
    const int q    = lane >> 4;           // quad 0..3
    const bool f32 = flags[0] != 0;

    const int row0 = bid * 32 + (w >> 1) * 16;  // wave's 16 rows
    const int ch   = w & 1;                     // this wave's col-half
    const int hd0  = ch * 2;                    // heads 0,1 or 2,3
    const ushort* wb = wbf + (size_t)ch * 16384;

    f32x4 acc[4];
    #pragma unroll
    for (int t = 0; t < 4; ++t) acc[t] = (f32x4){0.f, 0.f, 0.f, 0.f};

    if (f32){
        const float* xp = (const float*)xv_ + (size_t)(row0 + l15) * INF + q * 8;
        // 16 NAMED float4 loads, all issued before the MFMA loop (pinned).
        float4 a0 = ((const float4*)(xp +   0))[0], b0 = ((const float4*)(xp +   0))[1];
        float4 a1 = ((const float4*)(xp +  32))[0], b1 = ((const float4*)(xp +  32))[1];
        float4 a2 = ((const float4*)(xp +  64))[0], b2 = ((const float4*)(xp +  64))[1];
        float4 a3 = ((const float4*)(xp +  96))[0], b3 = ((const float4*)(xp +  96))[1];
        float4 a4 = ((const float4*)(xp + 128))[0], b4 = ((const float4*)(xp + 128))[1];
        float4 a5 = ((const float4*)(xp + 160))[0], b5 = ((const float4*)(xp + 160))[1];
        float4 a6 = ((const float4*)(xp + 192))[0], b6 = ((const float4*)(xp + 192))[1];
        float4 a7 = ((const float4*)(xp + 224))[0], b7 = ((const float4*)(xp + 224))[1];
        __builtin_amdgcn_sched_barrier(0);   // do NOT sink these loads

        #define KSTEP(KC, LO, HI)                                                        \
        {                                                                                \
            bf16x8 afrag;                                                                \
            afrag[0] = (short)f2bf_bits(LO.x); afrag[1] = (short)f2bf_bits(LO.y);        \
            afrag[2] = (short)f2bf_bits(LO.z); afrag[3] = (short)f2bf_bits(LO.w);        \
            afrag[4] = (short)f2bf_bits(HI.x); afrag[5] = (short)f2bf_bits(HI.y);        \
            afrag[6] = (short)f2bf_bits(HI.z); afrag[7] = (short)f2bf_bits(HI.w);        \
            _Pragma("unroll")                                                            \
            for (int t = 0; t < 4; ++t){                                                 \
                bf16x8 bfrag = *(const bf16x8*)(wb + (((size_t)(KC) * 4 + t) * 64 + lane) * 8); \
                acc[t] = __builtin_amdgcn_mfma_f32_16x16x32_bf16(afrag, bfrag, acc[t], 0, 0, 0); \
            }                                                                            \
        }
        KSTEP(0, a0, b0) KSTEP(1, a1, b1) KSTEP(2, a2, b2) KSTEP(3, a3, b3)
        KSTEP(4, a4, b4) KSTEP(5, a5, b5) KSTEP(6, a6, b6) KSTEP(7, a7, b7)
        #undef KSTEP
    } else {
        const ushort* xp = (const ushort*)xv_ + (size_t)(row0 + l15) * INF + q * 8;
        bf16x8 f0 = *(const bf16x8*)(xp +   0);
        bf16x8 f1 = *(const bf16x8*)(xp +  32);
        bf16x8 f2 = *(const bf16x8*)(xp +  64);
        bf16x8 f3 = *(const bf16x8*)(xp +  96);
        bf16x8 f4 = *(const bf16x8*)(xp + 128);
        bf16x8 f5 = *(const bf16x8*)(xp + 160);
        bf16x8 f6 = *(const bf16x8*)(xp + 192);
        bf16x8 f7 = *(const bf16x8*)(xp + 224);
        __builtin_amdgcn_sched_barrier(0);

        #define KSTEP(KC, AF)                                                            \
        {                                                                                \
            _Pragma("unroll")                                                            \
            for (int t = 0; t < 4; ++t){                                                 \
                bf16x8 bfrag = *(const bf16x8*)(wb + (((size_t)(KC) * 4 + t) * 64 + lane) * 8); \
                acc[t] = __builtin_amdgcn_mfma_f32_16x16x32_bf16(AF, bfrag, acc[t], 0, 0, 0); \
            }                                                                            \
        }
        KSTEP(0, f0) KSTEP(1, f1) KSTEP(2, f2) KSTEP(3, f3)
        KSTEP(4, f4) KSTEP(5, f5) KSTEP(6, f6) KSTEP(7, f7)
        #undef KSTEP
    }

    // ---- epilogue 1: h -> bf16, node-major interleaved [n][b][f*4+hd] ----
    #pragma unroll
    for (int r = 0; r < 4; ++r){
        int row = row0 + q * 4 + r;
        ushort* hp_ = h + hrow_of(row) * HF + hd0;
        #pragma unroll
        for (int t = 0; t < 2; ++t){    // t = f-half; f = t*16 + l15
            unsigned v = (unsigned)f2bf_bits(acc[t][r])
                       | ((unsigned)f2bf_bits(acc[t + 2][r]) << 16);  // this half's 2 heads
            int f = t * 16 + l15;
            *(unsigned*)(hp_ + f * 4) = v;
        }
    }

    // ---- epilogue 2: alpha dots from C registers (this col-half's 2 heads) ----
    float as_lo, as_hi, ad_lo, ad_hi;
    if (f32){
        const float* af = (const float*)av;
        as_lo = af[l15];        as_hi = af[16 + l15];
        ad_lo = af[OUTF + l15]; ad_hi = af[OUTF + 16 + l15];
    } else {
        const ushort* ab = (const ushort*)av;
        as_lo = bf2f(ab[l15]);        as_hi = bf2f(ab[16 + l15]);
        ad_lo = bf2f(ab[OUTF + l15]); ad_hi = bf2f(ab[OUTF + 16 + l15]);
    }
    #pragma unroll
    for (int r = 0; r < 4; ++r){
        int row = row0 + q * 4 + r;
        #pragma unroll
        for (int hp = 0; hp < 2; ++hp){
            int t0 = hp * 2, t1 = hp * 2 + 1;
            float ps = acc[t0][r] * as_lo + acc[t1][r] * as_hi;
            float pd = acc[t0][r] * ad_lo + acc[t1][r] * ad_hi;
            ps += __shfl_down(ps, 8, 16); pd += __shfl_down(pd, 8, 16);
            ps += __shfl_down(ps, 4, 16); pd += __shfl_down(pd, 4, 16);
            ps += __shfl_down(ps, 2, 16); pd += __shfl_down(pd, 2, 16);
            ps += __shfl_down(ps, 1, 16); pd += __shfl_down(pd, 1, 16);
            if (l15 == 0){
                size_t o = (size_t)row * NH + hd0 + hp;
                alpha_s[o] = ps;
                alpha_d[o] = pd;
            }
        }
    }
}

// K3 (fused aw+agg): one wave per node. Bucket walk reads packed u64 slots.
// THIS ROUND: 8 gathers in flight per iteration (was 4) — A/B for
// latency-bound vs L3-BW-bound regime of the gather phase.
__global__ __launch_bounds__(256)
void k_agg(const u64* __restrict__ slots, const int* __restrict__ cnt,
           const u64* __restrict__ last_e64,
           const float* __restrict__ alpha_s, const float* __restrict__ alpha_d,
           const ushort* __restrict__ h, float* __restrict__ aw,
           float* __restrict__ out_f){
    int lane = threadIdx.x & 63;
    int wid  = (blockIdx.x * blockDim.x + threadIdx.x) >> 6;
    int nw   = (gridDim.x * blockDim.x) >> 6;
    int b = lane >> 5;
    int f = lane & 31;
    int c  = lane & 7;          // softmax work item: bb = c>>2, hh = c&3
    int bb = c >> 2;
    int hh = c & 3;
    const ushort* hb = h + b * HF + f * 4;   // + d*HF2 per gather
    for (int n = wid; n < NN; n += nw){
        int m = cnt[n]; if (m > CAP) m = CAP;
        u64 le = last_e64[n];                 // 0 unless overflow happened

        const u64* sl = slots + (size_t)n * CAP;
        float ax = 0.f, ay = 0.f, az = 0.f, aww = 0.f;
        int i = 0;
        // 8-deep: 4 uniform 16B slot loads together, then 8 independent gathers.
        for (; i + 8 <= m; i += 8){
            ulonglong2 p0 = *(const ulonglong2*)(sl + i);
            ulonglong2 p1 = *(const ulonglong2*)(sl + i + 2);
            ulonglong2 p2 = *(const ulonglong2*)(sl + i + 4);
            ulonglong2 p3 = *(const ulonglong2*)(sl + i + 6);
            le = p0.x > le ? p0.x : le;  le = p0.y > le ? p0.y : le;
            le = p1.x > le ? p1.x : le;  le = p1.y > le ? p1.y : le;
            le = p2.x > le ? p2.x : le;  le = p2.y > le ? p2.y : le;
            le = p3.x > le ? p3.x : le;  le = p3.y > le ? p3.y : le;
            int d0 = (int)(p0.x & 0xFFFFULL);
            int d1 = (int)(p0.y & 0xFFFFULL);
            int d2 = (int)(p1.x & 0xFFFFULL);
            int d3 = (int)(p1.y & 0xFFFFULL);
            int d4 = (int)(p2.x & 0xFFFFULL);
            int d5 = (int)(p2.y & 0xFFFFULL);
            int d6 = (int)(p3.x & 0xFFFFULL);
            int d7 = (int)(p3.y & 0xFFFFULL);
            ushort4 u0 = *(const ushort4*)(hb + (size_t)d0 * HF2);
            ushort4 u1 = *(const ushort4*)(hb + (size_t)d1 * HF2);
            ushort4 u2 = *(const ushort4*)(hb + (size_t)d2 * HF2);
            ushort4 u3 = *(const ushort4*)(hb + (size_t)d3 * HF2);
            ushort4 u4 = *(const ushort4*)(hb + (size_t)d4 * HF2);
            ushort4 u5 = *(const ushort4*)(hb + (size_t)d5 * HF2);
            ushort4 u6 = *(const ushort4*)(hb + (size_t)d6 * HF2);
            ushort4 u7 = *(const ushort4*)(hb + (size_t)d7 * HF2);
            ax += bf2f(u0.x) + bf2f(u1.x) + bf2f(u2.x) + bf2f(u3.x)
                + bf2f(u4.x) + bf2f(u5.x) + bf2f(u6.x) + bf2f(u7.x);
            ay += bf2f(u0.y) + bf2f(u1.y) + bf2f(u2.y) + bf2f(u3.y)
                + bf2f(u4.y) + bf2f(u5.y) + bf2f(u6.y) + bf2f(u7.y);
            az += bf2f(u0.z) + bf2f(u1.z) + bf2f(u2.z) + bf2f(u3.z)
                + bf2f(u4.z) + bf2f(u5.z) + bf2f(u6.z) + bf2f(u7.z);
            aww += bf2f(u0.w) + bf2f(u1.w) + bf2f(u2.w) + bf2f(u3.w)
                 + bf2f(u4.w) + bf2f(u5.w) + bf2f(u6.w) + bf2f(u7.w);
        }
        for (; i + 4 <= m; i += 4){
            ulonglong2 p0 = *(const ulonglong2*)(sl + i);
            ulonglong2 p1 = *(const ulonglong2*)(sl + i + 2);
            le = p0.x > le ? p0.x : le;  le = p0.y > le ? p0.y : le;
            le = p1.x > le ? p1.x : le;  le = p1.y > le ? p1.y : le;
            int d0 = (int)(p0.x & 0xFFFFULL);
            int d1 = (int)(p0.y & 0xFFFFULL);
            int d2 = (int)(p1.x & 0xFFFFULL);
            int d3 = (int)(p1.y & 0xFFFFULL);
            ushort4 u0 = *(const ushort4*)(hb + (size_t)d0 * HF2);
            ushort4 u1 = *(const ushort4*)(hb + (size_t)d1 * HF2);
            ushort4 u2 = *(const ushort4*)(hb + (size_t)d2 * HF2);
            ushort4 u3 = *(const ushort4*)(hb + (size_t)d3 * HF2);
            ax += bf2f(u0.x) + bf2f(u1.x) + bf2f(u2.x) + bf2f(u3.x);
            ay += bf2f(u0.y) + bf2f(u1.y) + bf2f(u2.y) + bf2f(u3.y);
            az += bf2f(u0.z) + bf2f(u1.z) + bf2f(u2.z) + bf2f(u3.z);
            aww += bf2f(u0.w) + bf2f(u1.w) + bf2f(u2.w) + bf2f(u3.w);
        }
        for (; i < m; ++i){
            u64 pk = sl[i];
            le = pk > le ? pk : le;
            int d = (int)(pk & 0xFFFFULL);
            ushort4 u = *(const ushort4*)(hb + (size_t)d * HF2);
            ax += bf2f(u.x); ay += bf2f(u.y); az += bf2f(u.z); aww += bf2f(u.w);
        }

        // per-(bb,hh) attention weight (replicated x8 across the wave)
        float my_aw = 0.f;
        if (le != 0ULL){
            int d = (int)(le & 0xFFFFULL);      // dst of last edge: free
            float ss = alpha_s[((size_t)bb * NN + n) * NH + hh]
                     + alpha_d[((size_t)bb * NN + d) * NH + hh];
            float so = alpha_s[((size_t)(1 - bb) * NN + n) * NH + hh]
                     + alpha_d[((size_t)(1 - bb) * NN + d) * NH + hh];
            ss = ss > 0.f ? ss : NEG_SLOPE * ss;
            so = so > 0.f ? so : NEG_SLOPE * so;
            float mx = fmaxf(ss, so);
            float e0 = __expf(ss - mx);
            float e1 = __expf(so - mx);
            my_aw = 0.25f * e0 / (e0 + e1);
        }
        if (lane < 8) aw[((size_t)bb * NN + n) * NH + hh] = my_aw;  // for k_fix

        float aw0 = __shfl(my_aw, (b << 2) + 0, 8);
        float aw1 = __shfl(my_aw, (b << 2) + 1, 8);
        float aw2 = __shfl(my_aw, (b << 2) + 2, 8);
        float aw3 = __shfl(my_aw, (b << 2) + 3, 8);

        out_f[((size_t)b * NN + n) * OUTF + f] =
            aw0 * ax + aw1 * ay + aw2 * az + aw3 * aww;
    }
}

// K4: overflow fix-up (normally empty). One wave per overflow edge, atomics.
__global__ void k_fix(const int* __restrict__ ei, const int* __restrict__ flags,
                      const int* __restrict__ ovf_cnt, const int* __restrict__ ovf_list,
                      const ushort* __restrict__ h, const float* __restrict__ aw,
                      float* __restrict__ out_f){
    int lane = threadIdx.x & 63;
    int wid  = (blockIdx.x * blockDim.x + threadIdx.x) >> 6;
    int nw   = (gridDim.x * blockDim.x) >> 6;
    int b = lane >> 5;
    int f = lane & 31;
    int M = *ovf_cnt; if (M > OVF_CAP) M = OVF_CAP;
    int f64 = flags[1];
    for (int i = wid; i < M; i += nw){
        int e = ovf_list[i];
        int s = get_src(ei, e, f64);
        int d = get_dst(ei, e, f64);
        float4 awv = *(const float4*)(aw + ((size_t)b * NN + s) * NH);
        ushort4 u = *(const ushort4*)(h + ((size_t)d * 2 + b) * HF + f * 4);
        float acc = awv.x * bf2f(u.x) + awv.y * bf2f(u.y)
                  + awv.z * bf2f(u.z) + awv.w * bf2f(u.w);
        atomicAdd(&out_f[((size_t)b * NN + s) * OUTF + f], acc);
    }
}

extern "C" void kernel_launch(void* const* d_in, const int* in_sizes, int n_in,
                              void* d_out, int out_size, void* d_ws, size_t ws_size,
                              hipStream_t stream){
    const void* x = d_in[0]; const void* eiv = d_in[1];
    const void* W = d_in[2]; const void* a  = d_in[3];
    for (int i = 0; i < n_in; ++i){
        if      (in_sizes[i] == BB * NN * INF) x   = d_in[i];
        else if (in_sizes[i] == 2 * EE)        eiv = d_in[i];
        else if (in_sizes[i] == HF * INF)      W   = d_in[i];
        else if (in_sizes[i] == 2 * OUTF)      a   = d_in[i];
    }
    const int* ei = (const int*)eiv;
    float* out = (float*)d_out;    // output dtype: float32 (verified)

    // Workspace (~20.2 MiB): flags | wbf | h | alpha_s | alpha_d | aw
    //                        | last_e64 | cnt | ovf_cnt | ovf_list | slots(u64)
    const size_t HN = (size_t)BB * NN * HF;
    char* p = (char*)d_ws;
    int*   flags    = (int*)p;                        p += 64;
    ushort* wbf     = (ushort*)p;                     p += 32768 * 2;
    ushort* h       = (ushort*)p;                     p += HN * 2;
    float* alpha_s  = (float*)p;                      p += (size_t)BB * NN * NH * 4;
    float* alpha_d  = (float*)p;                      p += (size_t)BB * NN * NH * 4;
    float* aw       = (float*)p;                      p += (size_t)BB * NN * NH * 4;
    u64*   last_e64 = (u64*)p;                        p += (size_t)NN * 8;
    int*   cnt      = (int*)p;                        p += (size_t)NN * 4;
    int*   ovf_cnt  = (int*)p;                        p += 64;
    int*   ovf_list = (int*)p;                        p += (size_t)OVF_CAP * 4;
    u64*   slots    = (u64*)p;

    k_init <<<(NN + 255) / 256, 256, 0, stream>>>((const ushort*)x, ei, W, flags, wbf,
                                                  cnt, last_e64, ovf_cnt);
    k_gemm <<<EDGE_BLOCKS + GEMM_BLOCKS, 256, 0, stream>>>(x, wbf, a, ei, flags, h,
                                                           alpha_s, alpha_d, cnt,
                                                           slots, last_e64, ovf_cnt,
                                                           ovf_list);
    k_agg  <<<2048, 256, 0, stream>>>(slots, cnt, last_e64, alpha_s, alpha_d,
                                      h, aw, out);
    k_fix  <<<32, 256, 0, stream>>>(ei, flags, ovf_cnt, ovf_list, h, aw, out);
}

// Round 10
// 139.751 us; speedup vs baseline: 2.3061x; 1.0069x over previous
//
#include <hip/hip_runtime.h>
#include <hip/hip_bf16.h>

#define BB 2
#define NN 20000
#define EE 200000
#define INF 256
#define OUTF 32
#define NH 4
#define HF 128          // NH*OUTF
#define HF2 256         // 2*HF: node-major interleaved h row stride (ushorts)
#define NEG_SLOPE 0.2f
#define GEMM_BLOCKS 1250 // 40000 rows / 32; wave = 16 rows x 1 col-half
#define EDGE_BLOCKS 782  // ceil(200000/256), 1 edge per thread
#define CAP 48           // u64 slots per node (deg ~ Poisson(10); overflow -> list)
#define OVF_CAP 8192

using bf16 = __hip_bfloat16;
typedef __attribute__((ext_vector_type(8))) short bf16x8;
typedef __attribute__((ext_vector_type(4))) float f32x4;
typedef unsigned long long u64;

__device__ __forceinline__ float bf2f(unsigned short s){ return __uint_as_float((unsigned)s << 16); }
__device__ __forceinline__ ushort f2bf_bits(float f){
    __hip_bfloat16 b = __float2bfloat16(f);
    return *(ushort*)&b;
}

__device__ __forceinline__ int get_src(const int* ei, int e, int f64){
    return f64 ? ei[2 * e] : ei[e];
}
__device__ __forceinline__ int get_dst(const int* ei, int e, int f64){
    return f64 ? ei[2 * EE + 2 * e] : ei[EE + e];
}

// h layout: [node][b][f*4+hd] -> row stride HF2=256 ushorts (512B). Per edge,
// the agg wave (b=0: lanes 0-31, b=1: lanes 32-63) reads ONE contiguous 512B.
__device__ __forceinline__ size_t hrow_of(int row){   // row = b*NN + n
    return (row >= NN) ? ((size_t)(row - NN) * 2 + 1) : ((size_t)row * 2);
}

// K0: init cnt/last_e64/ovf; blocks 0..15: dtype-detect (each block re-derives
// the flag deterministically) + W -> bf16 B-frag-linear wbf.
__global__ void k_init(const ushort* __restrict__ xr, const int* __restrict__ er,
                       const void* __restrict__ Wv,
                       int* __restrict__ flags, ushort* __restrict__ wbf,
                       int* __restrict__ cnt, u64* __restrict__ last_e64,
                       int* __restrict__ ovf_cnt){
    int i = blockIdx.x * blockDim.x + threadIdx.x;
    if (i < NN){ cnt[i] = 0; last_e64[i] = 0ULL; }
    if (i == 0) *ovf_cnt = 0;
    if (blockIdx.x < 16){
        __shared__ int cnt_big, cnt_nz;
        if (threadIdx.x == 0){ cnt_big = 0; cnt_nz = 0; }
        __syncthreads();
        int big = 0;
        for (int k = threadIdx.x; k < 8192; k += blockDim.x){
            unsigned e = ((unsigned)xr[2 * k] >> 7) & 0xff;   // bf16-exp of fp32 low half
            if (e >= 0xC0) big++;                              // impossible for N(0,1) bf16
        }
        int nz = 0;
        for (int k = threadIdx.x; k < 4096; k += blockDim.x){
            if (er[2 * k + 1] != 0) nz++;                      // int64 high words all zero
        }
        atomicAdd(&cnt_big, big);
        atomicAdd(&cnt_nz, nz);
        __syncthreads();
        if (blockIdx.x == 0 && threadIdx.x == 0){
            flags[0] = (cnt_big >= 16) ? 1 : 0;
            flags[1] = (cnt_nz == 0) ? 1 : 0;
        }
        const bool f32w = (cnt_big >= 16);
        int fr = blockIdx.x * 256 + threadIdx.x;               // 0..4095
        {
            int lane = fr & 63;
            int t    = (fr >> 6) & 3;
            int kc   = (fr >> 8) & 7;
            int ch   = fr >> 11;
            int col  = ch * 64 + t * 16 + (lane & 15);
            int kb   = kc * 32 + (lane >> 4) * 8;
            bf16x8 v;
            if (f32w){
                const float* wg = (const float*)Wv + (size_t)col * INF + kb;
                #pragma unroll
                for (int j = 0; j < 8; ++j) v[j] = (short)f2bf_bits(wg[j]);
            } else {
                const ushort* wg = (const ushort*)Wv + (size_t)col * INF + kb;
                #pragma unroll
                for (int j = 0; j < 8; ++j) v[j] = (short)wg[j];
            }
            *(bf16x8*)(wbf + (size_t)fr * 8) = v;
        }
    }
}

// K1: MERGED edge-build + MFMA GEMM (heterogeneous blocks; edge blocks first).
// GEMM: 1250 blocks x 32 rows; wave = 16 rows x ONE col-half.
// All 16 x-loads issued as NAMED regs + sched_barrier(0) pin.
__global__ __launch_bounds__(256, 2)
void k_gemm(const void* __restrict__ xv_, const ushort* __restrict__ wbf,
            const void* __restrict__ av, const int* __restrict__ ei,
            const int* __restrict__ flags, ushort* __restrict__ h,
            float* __restrict__ alpha_s, float* __restrict__ alpha_d,
            int* __restrict__ cnt, u64* __restrict__ slots,
            u64* __restrict__ last_e64, int* __restrict__ ovf_cnt,
            int* __restrict__ ovf_list){
    if (blockIdx.x < EDGE_BLOCKS){
        int f64 = flags[1];
        int e = blockIdx.x * 256 + threadIdx.x;
        if (e < EE){
            int s = get_src(ei, e, f64);
            int d = get_dst(ei, e, f64);
            u64 pk = ((u64)(unsigned)(e + 1) << 16) | (unsigned)(d & 0xFFFF);
            int idx = atomicAdd(&cnt[s], 1);
            if (idx < CAP) slots[(size_t)s * CAP + idx] = pk;
            else {
                atomicMax(&last_e64[s], pk);    // rare: keeps le correct past CAP
                int o = atomicAdd(ovf_cnt, 1);
                if (o < OVF_CAP) ovf_list[o] = e;
            }
        }
        return;
    }

    const int bid  = blockIdx.x - EDGE_BLOCKS;
    const int tid  = threadIdx.x;
    const int lane = tid & 63;
    const int w    = tid >> 6;            // wave 0..3
    const int l15  = lane & 15;
    const int q    = lane >> 4;           // quad 0..3
    const bool f32 = flags[0] != 0;

    const int row0 = bid * 32 + (w >> 1) * 16;  // wave's 16 rows
    const int ch   = w & 1;                     // this wave's col-half
    const int hd0  = ch * 2;                    // heads 0,1 or 2,3
    const ushort* wb = wbf + (size_t)ch * 16384;

    f32x4 acc[4];
    #pragma unroll
    for (int t = 0; t < 4; ++t) acc[t] = (f32x4){0.f, 0.f, 0.f, 0.f};

    if (f32){
        const float* xp = (const float*)xv_ + (size_t)(row0 + l15) * INF + q * 8;
        // 16 NAMED float4 loads, all issued before the MFMA loop (pinned).
        float4 a0 = ((const float4*)(xp +   0))[0], b0 = ((const float4*)(xp +   0))[1];
        float4 a1 = ((const float4*)(xp +  32))[0], b1 = ((const float4*)(xp +  32))[1];
        float4 a2 = ((const float4*)(xp +  64))[0], b2 = ((const float4*)(xp +  64))[1];
        float4 a3 = ((const float4*)(xp +  96))[0], b3 = ((const float4*)(xp +  96))[1];
        float4 a4 = ((const float4*)(xp + 128))[0], b4 = ((const float4*)(xp + 128))[1];
        float4 a5 = ((const float4*)(xp + 160))[0], b5 = ((const float4*)(xp + 160))[1];
        float4 a6 = ((const float4*)(xp + 192))[0], b6 = ((const float4*)(xp + 192))[1];
        float4 a7 = ((const float4*)(xp + 224))[0], b7 = ((const float4*)(xp + 224))[1];
        __builtin_amdgcn_sched_barrier(0);   // do NOT sink these loads

        #define KSTEP(KC, LO, HI)                                                        \
        {                                                                                \
            bf16x8 afrag;                                                                \
            afrag[0] = (short)f2bf_bits(LO.x); afrag[1] = (short)f2bf_bits(LO.y);        \
            afrag[2] = (short)f2bf_bits(LO.z); afrag[3] = (short)f2bf_bits(LO.w);        \
            afrag[4] = (short)f2bf_bits(HI.x); afrag[5] = (short)f2bf_bits(HI.y);        \
            afrag[6] = (short)f2bf_bits(HI.z); afrag[7] = (short)f2bf_bits(HI.w);        \
            _Pragma("unroll")                                                            \
            for (int t = 0; t < 4; ++t){                                                 \
                bf16x8 bfrag = *(const bf16x8*)(wb + (((size_t)(KC) * 4 + t) * 64 + lane) * 8); \
                acc[t] = __builtin_amdgcn_mfma_f32_16x16x32_bf16(afrag, bfrag, acc[t], 0, 0, 0); \
            }                                                                            \
        }
        KSTEP(0, a0, b0) KSTEP(1, a1, b1) KSTEP(2, a2, b2) KSTEP(3, a3, b3)
        KSTEP(4, a4, b4) KSTEP(5, a5, b5) KSTEP(6, a6, b6) KSTEP(7, a7, b7)
        #undef KSTEP
    } else {
        const ushort* xp = (const ushort*)xv_ + (size_t)(row0 + l15) * INF + q * 8;
        bf16x8 f0 = *(const bf16x8*)(xp +   0);
        bf16x8 f1 = *(const bf16x8*)(xp +  32);
        bf16x8 f2 = *(const bf16x8*)(xp +  64);
        bf16x8 f3 = *(const bf16x8*)(xp +  96);
        bf16x8 f4 = *(const bf16x8*)(xp + 128);
        bf16x8 f5 = *(const bf16x8*)(xp + 160);
        bf16x8 f6 = *(const bf16x8*)(xp + 192);
        bf16x8 f7 = *(const bf16x8*)(xp + 224);
        __builtin_amdgcn_sched_barrier(0);

        #define KSTEP(KC, AF)                                                            \
        {                                                                                \
            _Pragma("unroll")                                                            \
            for (int t = 0; t < 4; ++t){                                                 \
                bf16x8 bfrag = *(const bf16x8*)(wb + (((size_t)(KC) * 4 + t) * 64 + lane) * 8); \
                acc[t] = __builtin_amdgcn_mfma_f32_16x16x32_bf16(AF, bfrag, acc[t], 0, 0, 0); \
            }                                                                            \
        }
        KSTEP(0, f0) KSTEP(1, f1) KSTEP(2, f2) KSTEP(3, f3)
        KSTEP(4, f4) KSTEP(5, f5) KSTEP(6, f6) KSTEP(7, f7)
        #undef KSTEP
    }

    // ---- epilogue 1: h -> bf16, node-major interleaved [n][b][f*4+hd] ----
    #pragma unroll
    for (int r = 0; r < 4; ++r){
        int row = row0 + q * 4 + r;
        ushort* hp_ = h + hrow_of(row) * HF + hd0;
        #pragma unroll
        for (int t = 0; t < 2; ++t){    // t = f-half; f = t*16 + l15
            unsigned v = (unsigned)f2bf_bits(acc[t][r])
                       | ((unsigned)f2bf_bits(acc[t + 2][r]) << 16);  // this half's 2 heads
            int f = t * 16 + l15;
            *(unsigned*)(hp_ + f * 4) = v;
        }
    }

    // ---- epilogue 2: alpha dots from C registers (this col-half's 2 heads) ----
    float as_lo, as_hi, ad_lo, ad_hi;
    if (f32){
        const float* af = (const float*)av;
        as_lo = af[l15];        as_hi = af[16 + l15];
        ad_lo = af[OUTF + l15]; ad_hi = af[OUTF + 16 + l15];
    } else {
        const ushort* ab = (const ushort*)av;
        as_lo = bf2f(ab[l15]);        as_hi = bf2f(ab[16 + l15]);
        ad_lo = bf2f(ab[OUTF + l15]); ad_hi = bf2f(ab[OUTF + 16 + l15]);
    }
    #pragma unroll
    for (int r = 0; r < 4; ++r){
        int row = row0 + q * 4 + r;
        #pragma unroll
        for (int hp = 0; hp < 2; ++hp){
            int t0 = hp * 2, t1 = hp * 2 + 1;
            float ps = acc[t0][r] * as_lo + acc[t1][r] * as_hi;
            float pd = acc[t0][r] * ad_lo + acc[t1][r] * ad_hi;
            ps += __shfl_down(ps, 8, 16); pd += __shfl_down(pd, 8, 16);
            ps += __shfl_down(ps, 4, 16); pd += __shfl_down(pd, 4, 16);
            ps += __shfl_down(ps, 2, 16); pd += __shfl_down(pd, 2, 16);
            ps += __shfl_down(ps, 1, 16); pd += __shfl_down(pd, 1, 16);
            if (l15 == 0){
                size_t o = (size_t)row * NH + hd0 + hp;
                alpha_s[o] = ps;
                alpha_d[o] = pd;
            }
        }
    }
}

// K3 (fused aw+agg+overflow-fix): one wave per node. Bucket walk reads packed
// u64 slots (8 gathers in flight). Overflow edges (normally NONE) are absorbed
// by the owning wave behind a wave-uniform *ovf_cnt check — k_fix dispatch and
// the aw[] global buffer are deleted.
__global__ __launch_bounds__(256)
void k_agg(const u64* __restrict__ slots, const int* __restrict__ cnt,
           const u64* __restrict__ last_e64,
           const float* __restrict__ alpha_s, const float* __restrict__ alpha_d,
           const ushort* __restrict__ h,
           const int* __restrict__ ei, const int* __restrict__ flags,
           const int* __restrict__ ovf_cnt, const int* __restrict__ ovf_list,
           float* __restrict__ out_f){
    int lane = threadIdx.x & 63;
    int wid  = (blockIdx.x * blockDim.x + threadIdx.x) >> 6;
    int nw   = (gridDim.x * blockDim.x) >> 6;
    int b = lane >> 5;
    int f = lane & 31;
    int c  = lane & 7;          // softmax work item: bb = c>>2, hh = c&3
    int bb = c >> 2;
    int hh = c & 3;
    int f64 = flags[1];
    const ushort* hb = h + b * HF + f * 4;   // + d*HF2 per gather
    for (int n = wid; n < NN; n += nw){
        int m = cnt[n]; if (m > CAP) m = CAP;
        u64 le = last_e64[n];                 // 0 unless overflow happened

        const u64* sl = slots + (size_t)n * CAP;
        float ax = 0.f, ay = 0.f, az = 0.f, aww = 0.f;
        int i = 0;
        // 8-deep: 4 uniform 16B slot loads together, then 8 independent gathers.
        for (; i + 8 <= m; i += 8){
            ulonglong2 p0 = *(const ulonglong2*)(sl + i);
            ulonglong2 p1 = *(const ulonglong2*)(sl + i + 2);
            ulonglong2 p2 = *(const ulonglong2*)(sl + i + 4);
            ulonglong2 p3 = *(const ulonglong2*)(sl + i + 6);
            le = p0.x > le ? p0.x : le;  le = p0.y > le ? p0.y : le;
            le = p1.x > le ? p1.x : le;  le = p1.y > le ? p1.y : le;
            le = p2.x > le ? p2.x : le;  le = p2.y > le ? p2.y : le;
            le = p3.x > le ? p3.x : le;  le = p3.y > le ? p3.y : le;
            int d0 = (int)(p0.x & 0xFFFFULL);
            int d1 = (int)(p0.y & 0xFFFFULL);
            int d2 = (int)(p1.x & 0xFFFFULL);
            int d3 = (int)(p1.y & 0xFFFFULL);
            int d4 = (int)(p2.x & 0xFFFFULL);
            int d5 = (int)(p2.y & 0xFFFFULL);
            int d6 = (int)(p3.x & 0xFFFFULL);
            int d7 = (int)(p3.y & 0xFFFFULL);
            ushort4 u0 = *(const ushort4*)(hb + (size_t)d0 * HF2);
            ushort4 u1 = *(const ushort4*)(hb + (size_t)d1 * HF2);
            ushort4 u2 = *(const ushort4*)(hb + (size_t)d2 * HF2);
            ushort4 u3 = *(const ushort4*)(hb + (size_t)d3 * HF2);
            ushort4 u4 = *(const ushort4*)(hb + (size_t)d4 * HF2);
            ushort4 u5 = *(const ushort4*)(hb + (size_t)d5 * HF2);
            ushort4 u6 = *(const ushort4*)(hb + (size_t)d6 * HF2);
            ushort4 u7 = *(const ushort4*)(hb + (size_t)d7 * HF2);
            ax += bf2f(u0.x) + bf2f(u1.x) + bf2f(u2.x) + bf2f(u3.x)
                + bf2f(u4.x) + bf2f(u5.x) + bf2f(u6.x) + bf2f(u7.x);
            ay += bf2f(u0.y) + bf2f(u1.y) + bf2f(u2.y) + bf2f(u3.y)
                + bf2f(u4.y) + bf2f(u5.y) + bf2f(u6.y) + bf2f(u7.y);
            az += bf2f(u0.z) + bf2f(u1.z) + bf2f(u2.z) + bf2f(u3.z)
                + bf2f(u4.z) + bf2f(u5.z) + bf2f(u6.z) + bf2f(u7.z);
            aww += bf2f(u0.w) + bf2f(u1.w) + bf2f(u2.w) + bf2f(u3.w)
                 + bf2f(u4.w) + bf2f(u5.w) + bf2f(u6.w) + bf2f(u7.w);
        }
        for (; i + 4 <= m; i += 4){
            ulonglong2 p0 = *(const ulonglong2*)(sl + i);
            ulonglong2 p1 = *(const ulonglong2*)(sl + i + 2);
            le = p0.x > le ? p0.x : le;  le = p0.y > le ? p0.y : le;
            le = p1.x > le ? p1.x : le;  le = p1.y > le ? p1.y : le;
            int d0 = (int)(p0.x & 0xFFFFULL);
            int d1 = (int)(p0.y & 0xFFFFULL);
            int d2 = (int)(p1.x & 0xFFFFULL);
            int d3 = (int)(p1.y & 0xFFFFULL);
            ushort4 u0 = *(const ushort4*)(hb + (size_t)d0 * HF2);
            ushort4 u1 = *(const ushort4*)(hb + (size_t)d1 * HF2);
            ushort4 u2 = *(const ushort4*)(hb + (size_t)d2 * HF2);
            ushort4 u3 = *(const ushort4*)(hb + (size_t)d3 * HF2);
            ax += bf2f(u0.x) + bf2f(u1.x) + bf2f(u2.x) + bf2f(u3.x);
            ay += bf2f(u0.y) + bf2f(u1.y) + bf2f(u2.y) + bf2f(u3.y);
            az += bf2f(u0.z) + bf2f(u1.z) + bf2f(u2.z) + bf2f(u3.z);
            aww += bf2f(u0.w) + bf2f(u1.w) + bf2f(u2.w) + bf2f(u3.w);
        }
        for (; i < m; ++i){
            u64 pk = sl[i];
            le = pk > le ? pk : le;
            int d = (int)(pk & 0xFFFFULL);
            ushort4 u = *(const ushort4*)(hb + (size_t)d * HF2);
            ax += bf2f(u.x); ay += bf2f(u.y); az += bf2f(u.z); aww += bf2f(u.w);
        }

        // ---- overflow absorb (wave-uniform branch; M == 0 in practice) ----
        int M = *ovf_cnt;
        if (M > 0){
            int Mc = M > OVF_CAP ? OVF_CAP : M;
            for (int k = 0; k < Mc; ++k){
                int e = ovf_list[k];
                if (get_src(ei, e, f64) == n){
                    int d = get_dst(ei, e, f64);
                    ushort4 u = *(const ushort4*)(hb + (size_t)d * HF2);
                    ax += bf2f(u.x); ay += bf2f(u.y);
                    az += bf2f(u.z); aww += bf2f(u.w);
                }
            }
        }

        // per-(bb,hh) attention weight (replicated x8 across the wave)
        float my_aw = 0.f;
        if (le != 0ULL){
            int d = (int)(le & 0xFFFFULL);      // dst of last edge: free
            float ss = alpha_s[((size_t)bb * NN + n) * NH + hh]
                     + alpha_d[((size_t)bb * NN + d) * NH + hh];
            float so = alpha_s[((size_t)(1 - bb) * NN + n) * NH + hh]
                     + alpha_d[((size_t)(1 - bb) * NN + d) * NH + hh];
            ss = ss > 0.f ? ss : NEG_SLOPE * ss;
            so = so > 0.f ? so : NEG_SLOPE * so;
            float mx = fmaxf(ss, so);
            float e0 = __expf(ss - mx);
            float e1 = __expf(so - mx);
            my_aw = 0.25f * e0 / (e0 + e1);
        }

        float aw0 = __shfl(my_aw, (b << 2) + 0, 8);
        float aw1 = __shfl(my_aw, (b << 2) + 1, 8);
        float aw2 = __shfl(my_aw, (b << 2) + 2, 8);
        float aw3 = __shfl(my_aw, (b << 2) + 3, 8);

        out_f[((size_t)b * NN + n) * OUTF + f] =
            aw0 * ax + aw1 * ay + aw2 * az + aw3 * aww;
    }
}

extern "C" void kernel_launch(void* const* d_in, const int* in_sizes, int n_in,
                              void* d_out, int out_size, void* d_ws, size_t ws_size,
                              hipStream_t stream){
    const void* x = d_in[0]; const void* eiv = d_in[1];
    const void* W = d_in[2]; const void* a  = d_in[3];
    for (int i = 0; i < n_in; ++i){
        if      (in_sizes[i] == BB * NN * INF) x   = d_in[i];
        else if (in_sizes[i] == 2 * EE)        eiv = d_in[i];
        else if (in_sizes[i] == HF * INF)      W   = d_in[i];
        else if (in_sizes[i] == 2 * OUTF)      a   = d_in[i];
    }
    const int* ei = (const int*)eiv;
    float* out = (float*)d_out;    // output dtype: float32 (verified)

    // Workspace (~19.5 MiB): flags | wbf | h | alpha_s | alpha_d
    //                        | last_e64 | cnt | ovf_cnt | ovf_list | slots(u64)
    const size_t HN = (size_t)BB * NN * HF;
    char* p = (char*)d_ws;
    int*   flags    = (int*)p;                        p += 64;
    ushort* wbf     = (ushort*)p;                     p += 32768 * 2;
    ushort* h       = (ushort*)p;                     p += HN * 2;
    float* alpha_s  = (float*)p;                      p += (size_t)BB * NN * NH * 4;
    float* alpha_d  = (float*)p;                      p += (size_t)BB * NN * NH * 4;
    u64*   last_e64 = (u64*)p;                        p += (size_t)NN * 8;
    int*   cnt      = (int*)p;                        p += (size_t)NN * 4;
    int*   ovf_cnt  = (int*)p;                        p += 64;
    int*   ovf_list = (int*)p;                        p += (size_t)OVF_CAP * 4;
    u64*   slots    = (u64*)p;

    k_init <<<(NN + 255) / 256, 256, 0, stream>>>((const ushort*)x, ei, W, flags, wbf,
                                                  cnt, last_e64, ovf_cnt);
    k_gemm <<<EDGE_BLOCKS + GEMM_BLOCKS, 256, 0, stream>>>(x, wbf, a, ei, flags, h,
                                                           alpha_s, alpha_d, cnt,
                                                           slots, last_e64, ovf_cnt,
                                                           ovf_list);
    k_agg  <<<2048, 256, 0, stream>>>(slots, cnt, last_e64, alpha_s, alpha_d,
                                      h, ei, flags, ovf_cnt, ovf_list, out);
}